// Round 1
// baseline (1772.362 us; speedup 1.0000x reference)
//
#include <hip/hip_runtime.h>

// LayerGIN MoE: gating(top-1 of 8) + sorted-CSR sparse aggregation +
// per-expert GEMM(200->128) + fused BN stats + BN-ReLU + GEMM(128->128)
// + fused BN stats + selective store + BN-ReLU-gate combine + aux losses.
// All fp32 this round (correctness-first; bf16/MFMA is the next lever).

#define NNODES 51200
#define CDIM   200
#define HDIM   128
#define NEXP   8
#define BNEPS  1e-5f

// ---------------------------------------------------------------- gating
__global__ __launch_bounds__(256) void gating_kernel(
    const float* __restrict__ v, const float* __restrict__ gW,
    const float* __restrict__ gb, int* __restrict__ top_idx,
    float* __restrict__ top_val, float* __restrict__ imp_acc,
    float* __restrict__ cnt_acc, float* __restrict__ tv_acc)
{
  __shared__ float s_imp[NEXP], s_cnt[NEXP], s_tv;
  const int tid = threadIdx.x, lane = tid & 63, wave = tid >> 6;
  if (tid < NEXP) { s_imp[tid] = 0.f; s_cnt[tid] = 0.f; }
  if (tid == 0) s_tv = 0.f;
  __syncthreads();
  for (int i = 0; i < 16; ++i) {
    const int node = blockIdx.x * 64 + wave * 16 + i;
    float p[NEXP];
#pragma unroll
    for (int e = 0; e < NEXP; ++e) p[e] = 0.f;
    const float* vr = v + (size_t)node * CDIM;
    for (int c = lane; c < CDIM; c += 64) {
      const float vv = vr[c];
      const float* g = gW + c * NEXP;
#pragma unroll
      for (int e = 0; e < NEXP; ++e) p[e] = fmaf(vv, g[e], p[e]);
    }
#pragma unroll
    for (int off = 32; off > 0; off >>= 1)
#pragma unroll
      for (int e = 0; e < NEXP; ++e) p[e] += __shfl_xor(p[e], off, 64);
#pragma unroll
    for (int e = 0; e < NEXP; ++e) p[e] += gb[e];
    float mx = p[0]; int ai = 0;
#pragma unroll
    for (int e = 1; e < NEXP; ++e) if (p[e] > mx) { mx = p[e]; ai = e; }
    float se = 0.f, pe[NEXP];
#pragma unroll
    for (int e = 0; e < NEXP; ++e) { pe[e] = __expf(p[e] - mx); se += pe[e]; }
    const float inv = 1.f / se;   // top prob = exp(0)/se
    if (lane == 0) {
      top_idx[node] = ai;
      top_val[node] = inv;
#pragma unroll
      for (int e = 0; e < NEXP; ++e) atomicAdd(&s_imp[e], pe[e] * inv);
      atomicAdd(&s_cnt[ai], 1.f);
      atomicAdd(&s_tv, inv);
    }
  }
  __syncthreads();
  if (tid < NEXP) { atomicAdd(&imp_acc[tid], s_imp[tid]); atomicAdd(&cnt_acc[tid], s_cnt[tid]); }
  if (tid == 0) atomicAdd(tv_acc, s_tv);
}

// ------------------------------------------------------- CSR build (sort)
__global__ __launch_bounds__(256) void hist_kernel(
    const int* __restrict__ rows, int* __restrict__ counts, int ne)
{
  const int i = blockIdx.x * 256 + threadIdx.x;
  if (i < ne) atomicAdd(&counts[rows[i]], 1);
}

__global__ __launch_bounds__(1024) void scan_kernel(
    const int* __restrict__ counts, int* __restrict__ row_start,
    int* __restrict__ cursors, int n)
{
  __shared__ int sh[1024];
  __shared__ int carry;
  const int tid = threadIdx.x;
  if (tid == 0) carry = 0;
  __syncthreads();
  for (int base = 0; base < n; base += 1024) {
    const int idx = base + tid;
    const int val = (idx < n) ? counts[idx] : 0;
    sh[tid] = val;
    __syncthreads();
    for (int off = 1; off < 1024; off <<= 1) {
      const int t = (tid >= off) ? sh[tid - off] : 0;
      __syncthreads();
      sh[tid] += t;
      __syncthreads();
    }
    const int inc = sh[tid];
    if (idx < n) {
      const int s = carry + inc - val;   // exclusive
      row_start[idx] = s;
      cursors[idx]   = s;
    }
    __syncthreads();
    if (tid == 1023) carry += inc;
    __syncthreads();
  }
}

__global__ __launch_bounds__(256) void scatter_kernel(
    const int* __restrict__ rows, const int* __restrict__ cols,
    const float* __restrict__ vals, int* __restrict__ cursors,
    int2* __restrict__ cv, int ne)
{
  const int i = blockIdx.x * 256 + threadIdx.x;
  if (i < ne) {
    const int pos = atomicAdd(&cursors[rows[i]], 1);
    cv[pos] = make_int2(cols[i], __float_as_int(vals[i]));
  }
}

// one wave per destination node; accumulate its ~32 neighbors in registers
__global__ __launch_bounds__(256) void aggregate_kernel(
    const float* __restrict__ v, const int2* __restrict__ cv,
    const int* __restrict__ row_start, const int* __restrict__ counts,
    float* __restrict__ agg)
{
  const int node = (blockIdx.x * 256 + threadIdx.x) >> 6;
  const int lane = threadIdx.x & 63;
  const int start = row_start[node];
  const int cnt   = counts[node];
  float a0 = 0.f, a1 = 0.f, a2 = 0.f, a3 = 0.f;
  for (int k = 0; k < cnt; ++k) {
    const int2 e = cv[start + k];
    const float val = __int_as_float(e.y);
    const float* vr = v + (size_t)e.x * CDIM;
    a0 = fmaf(val, vr[lane], a0);
    a1 = fmaf(val, vr[lane + 64], a1);
    a2 = fmaf(val, vr[lane + 128], a2);
    if (lane < CDIM - 192) a3 = fmaf(val, vr[lane + 192], a3);
  }
  float* ar = agg + (size_t)node * CDIM;
  ar[lane] = a0; ar[lane + 64] = a1; ar[lane + 128] = a2;
  if (lane < CDIM - 192) ar[lane + 192] = a3;
}

// ------------------------------------------------------------- GEMM 1
// h1[slot,n,h] = (agg[n,:] + (1+eps_e) v[n,:]) @ W1[e] + b1[e]; fused BN stats
__global__ __launch_bounds__(256) void gemm1_kernel(
    const float* __restrict__ agg, const float* __restrict__ v,
    const float* __restrict__ W1, const float* __restrict__ b1,
    const float* __restrict__ eps, float* __restrict__ h1,
    float* __restrict__ sum1, float* __restrict__ sq1, int e0)
{
  const int slot = blockIdx.y;
  const int e = e0 + slot;
  const int m0 = blockIdx.x * 64;
  const float se = 1.f + eps[e];
  __shared__ float As[8][68];
  __shared__ float Bs[8][132];
  __shared__ float ssum[HDIM], ssq[HDIM];
  const int tid = threadIdx.x;
  const int cA   = (tid & 15) * 4;      // cols cA..cA+3 and cA+64..cA+67
  const int row0 = (tid >> 4) * 4;
  const int am = tid >> 2, ak = (tid & 3) * 2;
  const int bk = tid >> 5, bh = (tid & 31) * 4;
  float acc[4][8];
  const float* b1e = b1 + e * HDIM;
#pragma unroll
  for (int j = 0; j < 4; ++j) {
    const float v0 = b1e[cA + j], v1 = b1e[cA + 64 + j];
#pragma unroll
    for (int i = 0; i < 4; ++i) { acc[i][j] = v0; acc[i][4 + j] = v1; }
  }
  const float* W1e = W1 + (size_t)e * CDIM * HDIM;
  const size_t arow = (size_t)(m0 + am) * CDIM;
  for (int k0 = 0; k0 < CDIM; k0 += 8) {
    const float2 ag = *(const float2*)(agg + arow + k0 + ak);
    const float2 vv = *(const float2*)(v + arow + k0 + ak);
    As[ak][am]     = fmaf(se, vv.x, ag.x);
    As[ak + 1][am] = fmaf(se, vv.y, ag.y);
    *(float4*)&Bs[bk][bh] = *(const float4*)(W1e + (size_t)(k0 + bk) * HDIM + bh);
    __syncthreads();
#pragma unroll
    for (int kk = 0; kk < 8; ++kk) {
      const float4 a4 = *(const float4*)&As[kk][row0];
      const float4 bA = *(const float4*)&Bs[kk][cA];
      const float4 bB = *(const float4*)&Bs[kk][cA + 64];
      const float ar[4] = {a4.x, a4.y, a4.z, a4.w};
      const float br[8] = {bA.x, bA.y, bA.z, bA.w, bB.x, bB.y, bB.z, bB.w};
#pragma unroll
      for (int i = 0; i < 4; ++i)
#pragma unroll
        for (int j = 0; j < 8; ++j) acc[i][j] = fmaf(ar[i], br[j], acc[i][j]);
    }
    __syncthreads();
  }
  float* h1e = h1 + ((size_t)slot * NNODES + m0) * HDIM;
#pragma unroll
  for (int i = 0; i < 4; ++i) {
    const size_t r = (size_t)(row0 + i) * HDIM;
    *(float4*)(h1e + r + cA)      = make_float4(acc[i][0], acc[i][1], acc[i][2], acc[i][3]);
    *(float4*)(h1e + r + cA + 64) = make_float4(acc[i][4], acc[i][5], acc[i][6], acc[i][7]);
  }
  if (tid < HDIM) { ssum[tid] = 0.f; ssq[tid] = 0.f; }
  __syncthreads();
#pragma unroll
  for (int j = 0; j < 8; ++j) {
    const int col = (j < 4) ? (cA + j) : (cA + 60 + j);
    float s = 0.f, q = 0.f;
#pragma unroll
    for (int i = 0; i < 4; ++i) { const float x = acc[i][j]; s += x; q = fmaf(x, x, q); }
    atomicAdd(&ssum[col], s);
    atomicAdd(&ssq[col], q);
  }
  __syncthreads();
  if (tid < HDIM) {
    atomicAdd(&sum1[e * HDIM + tid], ssum[tid]);
    atomicAdd(&sq1[e * HDIM + tid], ssq[tid]);
  }
}

// mean/invstd -> affine scale/shift for BN(+g,beta)
__global__ __launch_bounds__(128) void finalize_kernel(
    const float* __restrict__ sum, const float* __restrict__ sq,
    const float* __restrict__ g, const float* __restrict__ beta,
    float* __restrict__ scale, float* __restrict__ shift, int e0)
{
  const int i = (e0 + blockIdx.x) * HDIM + threadIdx.x;
  const float invN = 1.f / (float)NNODES;
  const float mean = sum[i] * invN;
  const float var  = sq[i] * invN - mean * mean;
  const float sc = rsqrtf(var + BNEPS) * g[i];
  scale[i] = sc;
  shift[i] = fmaf(-mean, sc, beta[i]);
}

// ------------------------------------------------------------- GEMM 2
// h2 = relu(h1*scaleA+shiftA) @ W2[e] + b2[e]; fused BN2 stats; store only
// rows whose top-1 expert == e.
__global__ __launch_bounds__(256) void gemm2_kernel(
    const float* __restrict__ h1, const float* __restrict__ W2,
    const float* __restrict__ b2, const float* __restrict__ scaleA,
    const float* __restrict__ shiftA, const int* __restrict__ top_idx,
    float* __restrict__ h2_sel, float* __restrict__ sum2,
    float* __restrict__ sq2, int e0)
{
  const int slot = blockIdx.y;
  const int e = e0 + slot;
  const int m0 = blockIdx.x * 64;
  __shared__ float As[8][68];
  __shared__ float Bs[8][132];
  __shared__ float ssum[HDIM], ssq[HDIM];
  const int tid = threadIdx.x;
  const int cA   = (tid & 15) * 4;
  const int row0 = (tid >> 4) * 4;
  const int am = tid >> 2, ak = (tid & 3) * 2;
  const int bk = tid >> 5, bh = (tid & 31) * 4;
  float acc[4][8];
  const float* b2e = b2 + e * HDIM;
#pragma unroll
  for (int j = 0; j < 4; ++j) {
    const float v0 = b2e[cA + j], v1 = b2e[cA + 64 + j];
#pragma unroll
    for (int i = 0; i < 4; ++i) { acc[i][j] = v0; acc[i][4 + j] = v1; }
  }
  const float* W2e = W2 + (size_t)e * HDIM * HDIM;
  const float* scA = scaleA + e * HDIM;
  const float* shA = shiftA + e * HDIM;
  const float* h1e = h1 + (size_t)slot * NNODES * HDIM;
  const size_t arow = (size_t)(m0 + am) * HDIM;
  for (int k0 = 0; k0 < HDIM; k0 += 8) {
    const int c = k0 + ak;
    const float2 hv = *(const float2*)(h1e + arow + c);
    const float2 sc = *(const float2*)(scA + c);
    const float2 sh = *(const float2*)(shA + c);
    As[ak][am]     = fmaxf(0.f, fmaf(hv.x, sc.x, sh.x));
    As[ak + 1][am] = fmaxf(0.f, fmaf(hv.y, sc.y, sh.y));
    *(float4*)&Bs[bk][bh] = *(const float4*)(W2e + (size_t)(k0 + bk) * HDIM + bh);
    __syncthreads();
#pragma unroll
    for (int kk = 0; kk < 8; ++kk) {
      const float4 a4 = *(const float4*)&As[kk][row0];
      const float4 bA = *(const float4*)&Bs[kk][cA];
      const float4 bB = *(const float4*)&Bs[kk][cA + 64];
      const float ar[4] = {a4.x, a4.y, a4.z, a4.w};
      const float br[8] = {bA.x, bA.y, bA.z, bA.w, bB.x, bB.y, bB.z, bB.w};
#pragma unroll
      for (int i = 0; i < 4; ++i)
#pragma unroll
        for (int j = 0; j < 8; ++j) acc[i][j] = fmaf(ar[i], br[j], acc[i][j]);
    }
    __syncthreads();
  }
  // selective store of raw h2 rows
#pragma unroll
  for (int i = 0; i < 4; ++i) {
    const int n = m0 + row0 + i;
    if (top_idx[n] == e) {
      float* r = h2_sel + (size_t)n * HDIM;
      *(float4*)(r + cA)      = make_float4(acc[i][0], acc[i][1], acc[i][2], acc[i][3]);
      *(float4*)(r + cA + 64) = make_float4(acc[i][4], acc[i][5], acc[i][6], acc[i][7]);
    }
  }
  if (tid < HDIM) { ssum[tid] = 0.f; ssq[tid] = 0.f; }
  __syncthreads();
#pragma unroll
  for (int j = 0; j < 8; ++j) {
    const int col = (j < 4) ? (cA + j) : (cA + 60 + j);
    float s = 0.f, q = 0.f;
#pragma unroll
    for (int i = 0; i < 4; ++i) { const float x = acc[i][j]; s += x; q = fmaf(x, x, q); }
    atomicAdd(&ssum[col], s);
    atomicAdd(&ssq[col], q);
  }
  __syncthreads();
  if (tid < HDIM) {
    atomicAdd(&sum2[e * HDIM + tid], ssum[tid]);
    atomicAdd(&sq2[e * HDIM + tid], ssq[tid]);
  }
}

// --------------------------------------------------------- combine + loss
__global__ __launch_bounds__(256) void combine_kernel(
    const float* __restrict__ h2_sel, const int* __restrict__ top_idx,
    const float* __restrict__ top_val, const float* __restrict__ scale2,
    const float* __restrict__ shift2, float* __restrict__ out)
{
  const int i4 = (blockIdx.x * 256 + threadIdx.x) * 4;
  const int n = i4 >> 7, h = i4 & 127;
  const int e = top_idx[n];
  const float tv = top_val[n];
  const float4 x = *(const float4*)(h2_sel + i4);
  const float* sc = scale2 + e * HDIM + h;
  const float* sh = shift2 + e * HDIM + h;
  float4 o;
  o.x = tv * fmaxf(0.f, fmaf(x.x, sc[0], sh[0]));
  o.y = tv * fmaxf(0.f, fmaf(x.y, sc[1], sh[1]));
  o.z = tv * fmaxf(0.f, fmaf(x.z, sc[2], sh[2]));
  o.w = tv * fmaxf(0.f, fmaf(x.w, sc[3], sh[3]));
  *(float4*)(out + i4) = o;
}

__global__ void loss_kernel(const float* __restrict__ imp,
                            const float* __restrict__ cnt,
                            const float* __restrict__ tv,
                            float* __restrict__ out_losses)
{
  if (threadIdx.x == 0) {
    const float invN = 1.f / (float)NNODES;
    float bal = 0.f;
#pragma unroll
    for (int e = 0; e < NEXP; ++e) bal += (imp[e] * invN) * (cnt[e] * invN);
    out_losses[0] = 0.01f * (float)NEXP * bal;
    out_losses[1] = -0.01f * tv[0] * invN;
  }
}

// ----------------------------------------------------------------- launch
struct WS {
  float *agg, *h1, *h2_sel;
  int2 *cv;
  int *row_start, *cursors, *top_idx;
  float *top_val;
  char *zero_base; size_t zero_bytes;
  int *counts;
  float *sum1, *sq1, *sum2, *sq2, *imp, *cnt, *tv;
  float *scaleA, *shiftA, *scale2, *shift2;
  size_t total;
};

static WS carve_ws(char* base, int ecnt, int ne)
{
  WS w; size_t off = 0;
  auto take = [&](size_t b) -> char* {
    char* r = base + off; off += (b + 255) & ~(size_t)255; return r;
  };
  w.agg      = (float*)take((size_t)NNODES * CDIM * 4);
  w.h1       = (float*)take((size_t)ecnt * NNODES * HDIM * 4);
  w.h2_sel   = (float*)take((size_t)NNODES * HDIM * 4);
  w.cv       = (int2*)take((size_t)ne * 8);
  w.row_start= (int*)take(NNODES * 4);
  w.cursors  = (int*)take(NNODES * 4);
  w.top_idx  = (int*)take(NNODES * 4);
  w.top_val  = (float*)take(NNODES * 4);
  w.zero_base = base + off;
  w.counts = (int*)take(NNODES * 4);
  w.sum1 = (float*)take(NEXP * HDIM * 4);
  w.sq1  = (float*)take(NEXP * HDIM * 4);
  w.sum2 = (float*)take(NEXP * HDIM * 4);
  w.sq2  = (float*)take(NEXP * HDIM * 4);
  w.imp  = (float*)take(NEXP * 4);
  w.cnt  = (float*)take(NEXP * 4);
  w.tv   = (float*)take(4);
  w.zero_bytes = (size_t)((base + off) - w.zero_base);
  w.scaleA = (float*)take(NEXP * HDIM * 4);
  w.shiftA = (float*)take(NEXP * HDIM * 4);
  w.scale2 = (float*)take(NEXP * HDIM * 4);
  w.shift2 = (float*)take(NEXP * HDIM * 4);
  w.total = off;
  return w;
}

extern "C" void kernel_launch(void* const* d_in, const int* in_sizes, int n_in,
                              void* d_out, int out_size, void* d_ws, size_t ws_size,
                              hipStream_t stream)
{
  const float* v      = (const float*)d_in[0];
  const int*   a_rows = (const int*)d_in[1];
  const int*   a_cols = (const int*)d_in[2];
  const float* a_vals = (const float*)d_in[3];
  const float* gate_W = (const float*)d_in[4];
  const float* gate_b = (const float*)d_in[5];
  const float* eps    = (const float*)d_in[6];
  const float* W1     = (const float*)d_in[7];
  const float* b1     = (const float*)d_in[8];
  const float* g1     = (const float*)d_in[9];
  const float* beta1  = (const float*)d_in[10];
  const float* W2     = (const float*)d_in[11];
  const float* b2     = (const float*)d_in[12];
  const float* g2     = (const float*)d_in[13];
  const float* beta2  = (const float*)d_in[14];
  const int NE = in_sizes[1];
  float* out = (float*)d_out;
  (void)n_in; (void)out_size;

  int ecnt = NEXP;
  WS w = carve_ws((char*)d_ws, ecnt, NE);
  if (w.total > ws_size) { ecnt = 1; w = carve_ws((char*)d_ws, ecnt, NE); }

  hipMemsetAsync(w.zero_base, 0, w.zero_bytes, stream);

  gating_kernel<<<NNODES / 64, 256, 0, stream>>>(
      v, gate_W, gate_b, w.top_idx, w.top_val, w.imp, w.cnt, w.tv);
  hist_kernel<<<(NE + 255) / 256, 256, 0, stream>>>(a_rows, w.counts, NE);
  scan_kernel<<<1, 1024, 0, stream>>>(w.counts, w.row_start, w.cursors, NNODES);
  scatter_kernel<<<(NE + 255) / 256, 256, 0, stream>>>(
      a_rows, a_cols, a_vals, w.cursors, w.cv, NE);
  aggregate_kernel<<<NNODES / 4, 256, 0, stream>>>(
      v, w.cv, w.row_start, w.counts, w.agg);

  for (int e0 = 0; e0 < NEXP; e0 += ecnt) {
    dim3 grid(NNODES / 64, ecnt);
    gemm1_kernel<<<grid, 256, 0, stream>>>(
        w.agg, v, W1, b1, eps, w.h1, w.sum1, w.sq1, e0);
    finalize_kernel<<<ecnt, 128, 0, stream>>>(
        w.sum1, w.sq1, g1, beta1, w.scaleA, w.shiftA, e0);
    gemm2_kernel<<<grid, 256, 0, stream>>>(
        w.h1, W2, b2, w.scaleA, w.shiftA, w.top_idx,
        w.h2_sel, w.sum2, w.sq2, e0);
    finalize_kernel<<<ecnt, 128, 0, stream>>>(
        w.sum2, w.sq2, g2, beta2, w.scale2, w.shift2, e0);
  }

  combine_kernel<<<(NNODES * HDIM) / 1024, 256, 0, stream>>>(
      w.h2_sel, w.top_idx, w.top_val, w.scale2, w.shift2, out);
  loss_kernel<<<1, 64, 0, stream>>>(w.imp, w.cnt, w.tv, out + (size_t)NNODES * HDIM);
}

// Round 2
// 837.425 us; speedup vs baseline: 2.1164x; 2.1164x over previous
//
#include <hip/hip_runtime.h>

// LayerGIN MoE — round 2: bf16 MFMA GEMMs (32x32x16), float4 aggregate gather,
// multi-block scan. BN makes biases b1/b2 mathematically irrelevant (constant
// per-channel shift cancels in h - mu), so they are skipped entirely.

#define NNODES 51200
#define CDIM   200
#define HDIM   128
#define NEXP   8
#define BNEPS  1e-5f
#define KS1    13   // ceil(200/16)
#define KS2    8    // 128/16

typedef __attribute__((ext_vector_type(8)))  short short8;
typedef __attribute__((ext_vector_type(16))) float floatx16;

__device__ __forceinline__ unsigned short f2bf(float x) {
  unsigned int u = __float_as_uint(x);
  u += 0x7fffu + ((u >> 16) & 1u);           // round-to-nearest-even
  return (unsigned short)(u >> 16);
}
__device__ __forceinline__ float bf2f(unsigned short h) {
  return __uint_as_float(((unsigned int)h) << 16);
}

// ---------------------------------------------------------------- gating
__global__ __launch_bounds__(256) void gating_kernel(
    const float* __restrict__ v, const float* __restrict__ gW,
    const float* __restrict__ gb, int* __restrict__ top_idx,
    float* __restrict__ top_val, float* __restrict__ imp_acc,
    float* __restrict__ cnt_acc, float* __restrict__ tv_acc)
{
  __shared__ float s_imp[NEXP], s_cnt[NEXP], s_tv;
  const int tid = threadIdx.x, lane = tid & 63, wave = tid >> 6;
  if (tid < NEXP) { s_imp[tid] = 0.f; s_cnt[tid] = 0.f; }
  if (tid == 0) s_tv = 0.f;
  __syncthreads();
  for (int i = 0; i < 16; ++i) {
    const int node = blockIdx.x * 64 + wave * 16 + i;
    float p[NEXP];
#pragma unroll
    for (int e = 0; e < NEXP; ++e) p[e] = 0.f;
    const float* vr = v + (size_t)node * CDIM;
    for (int c = lane; c < CDIM; c += 64) {
      const float vv = vr[c];
      const float* g = gW + c * NEXP;
#pragma unroll
      for (int e = 0; e < NEXP; ++e) p[e] = fmaf(vv, g[e], p[e]);
    }
#pragma unroll
    for (int off = 32; off > 0; off >>= 1)
#pragma unroll
      for (int e = 0; e < NEXP; ++e) p[e] += __shfl_xor(p[e], off, 64);
#pragma unroll
    for (int e = 0; e < NEXP; ++e) p[e] += gb[e];
    float mx = p[0]; int ai = 0;
#pragma unroll
    for (int e = 1; e < NEXP; ++e) if (p[e] > mx) { mx = p[e]; ai = e; }
    float se = 0.f, pe[NEXP];
#pragma unroll
    for (int e = 0; e < NEXP; ++e) { pe[e] = __expf(p[e] - mx); se += pe[e]; }
    const float inv = 1.f / se;
    if (lane == 0) {
      top_idx[node] = ai;
      top_val[node] = inv;
#pragma unroll
      for (int e = 0; e < NEXP; ++e) atomicAdd(&s_imp[e], pe[e] * inv);
      atomicAdd(&s_cnt[ai], 1.f);
      atomicAdd(&s_tv, inv);
    }
  }
  __syncthreads();
  if (tid < NEXP) { atomicAdd(&imp_acc[tid], s_imp[tid]); atomicAdd(&cnt_acc[tid], s_cnt[tid]); }
  if (tid == 0) atomicAdd(tv_acc, s_tv);
}

// ------------------------------------------------------- CSR build (sort)
__global__ __launch_bounds__(256) void hist_kernel(
    const int* __restrict__ rows, int* __restrict__ counts, int ne)
{
  const int i = blockIdx.x * 256 + threadIdx.x;
  if (i < ne) atomicAdd(&counts[rows[i]], 1);
}

__global__ __launch_bounds__(1024) void scan_block_kernel(
    const int* __restrict__ counts, int* __restrict__ incl, int* __restrict__ bsum)
{
  __shared__ int sh[1024];
  const int tid = threadIdx.x;
  const int idx = blockIdx.x * 1024 + tid;
  sh[tid] = counts[idx];
  __syncthreads();
  for (int off = 1; off < 1024; off <<= 1) {
    const int t = (tid >= off) ? sh[tid - off] : 0;
    __syncthreads();
    sh[tid] += t;
    __syncthreads();
  }
  incl[idx] = sh[tid];
  if (tid == 1023) bsum[blockIdx.x] = sh[tid];
}

__global__ void scan_tops_kernel(const int* __restrict__ bsum,
                                 int* __restrict__ boff, int nb)
{
  const int lane = threadIdx.x;
  const int v = (lane < nb) ? bsum[lane] : 0;
  int incl = v;
#pragma unroll
  for (int off = 1; off < 64; off <<= 1) {
    const int t = __shfl_up(incl, off, 64);
    if (lane >= off) incl += t;
  }
  if (lane < nb) boff[lane] = incl - v;
}

__global__ __launch_bounds__(256) void scan_apply_kernel(
    const int* __restrict__ incl, const int* __restrict__ boff,
    const int* __restrict__ counts, int* __restrict__ row_start,
    int* __restrict__ cursors)
{
  const int i = blockIdx.x * 256 + threadIdx.x;
  const int s = boff[i >> 10] + incl[i] - counts[i];
  row_start[i] = s;
  cursors[i] = s;
}

__global__ __launch_bounds__(256) void scatter_kernel(
    const int* __restrict__ rows, const int* __restrict__ cols,
    const float* __restrict__ vals, int* __restrict__ cursors,
    int2* __restrict__ cv, int ne)
{
  const int i = blockIdx.x * 256 + threadIdx.x;
  if (i < ne) {
    const int pos = atomicAdd(&cursors[rows[i]], 1);
    cv[pos] = make_int2(cols[i], __float_as_int(vals[i]));
  }
}

// one wave per destination node; float4 gather, 2-edge unroll for MLP
__global__ __launch_bounds__(256) void aggregate_kernel(
    const float* __restrict__ v, const int2* __restrict__ cv,
    const int* __restrict__ row_start, const int* __restrict__ counts,
    float* __restrict__ agg)
{
  const int node = (blockIdx.x * 256 + threadIdx.x) >> 6;
  const int lane = threadIdx.x & 63;
  const int start = row_start[node];
  const int cnt   = counts[node];
  const bool act  = lane < 50;            // 50 * float4 = 200 floats
  float4 a = make_float4(0.f, 0.f, 0.f, 0.f);
  int k = 0;
  for (; k + 2 <= cnt; k += 2) {
    const int2 e0 = cv[start + k];
    const int2 e1 = cv[start + k + 1];
    float4 x0 = make_float4(0,0,0,0), x1 = make_float4(0,0,0,0);
    if (act) {
      x0 = *((const float4*)(v + (size_t)e0.x * CDIM) + lane);
      x1 = *((const float4*)(v + (size_t)e1.x * CDIM) + lane);
    }
    const float v0 = __int_as_float(e0.y), v1 = __int_as_float(e1.y);
    a.x = fmaf(v0, x0.x, a.x); a.y = fmaf(v0, x0.y, a.y);
    a.z = fmaf(v0, x0.z, a.z); a.w = fmaf(v0, x0.w, a.w);
    a.x = fmaf(v1, x1.x, a.x); a.y = fmaf(v1, x1.y, a.y);
    a.z = fmaf(v1, x1.z, a.z); a.w = fmaf(v1, x1.w, a.w);
  }
  if (k < cnt) {
    const int2 e0 = cv[start + k];
    float4 x0 = make_float4(0,0,0,0);
    if (act) x0 = *((const float4*)(v + (size_t)e0.x * CDIM) + lane);
    const float v0 = __int_as_float(e0.y);
    a.x = fmaf(v0, x0.x, a.x); a.y = fmaf(v0, x0.y, a.y);
    a.z = fmaf(v0, x0.z, a.z); a.w = fmaf(v0, x0.w, a.w);
  }
  if (act) *((float4*)(agg + (size_t)node * CDIM) + lane) = a;
}

// ------------------------------------------- weight pre-transpose+convert
// W[e][k][n] (fp32) -> Bt[e][ks][kh][n][8] (bf16), zero-padded past K.
__global__ __launch_bounds__(256) void btconv_kernel(
    const float* __restrict__ W, unsigned short* __restrict__ Bt, int K, int nks)
{
  const int e = blockIdx.y, ks = blockIdx.x;
  __shared__ float tile[16][128];
  const int tid = threadIdx.x;
  const int kr = tid >> 5, n4 = (tid & 31) * 4;
#pragma unroll
  for (int h = 0; h < 2; ++h) {
    const int k = ks * 16 + kr + h * 8;
    float4 val = make_float4(0.f, 0.f, 0.f, 0.f);
    if (k < K) val = *(const float4*)(W + ((size_t)e * K + k) * HDIM + n4);
    *(float4*)&tile[kr + h * 8][n4] = val;
  }
  __syncthreads();
  const int kh = tid >> 7, n = tid & 127;
  short8 pk;
#pragma unroll
  for (int j = 0; j < 8; ++j) pk[j] = (short)f2bf(tile[kh * 8 + j][n]);
  *(short8*)(Bt + (((size_t)e * nks + ks) * 256 + tid) * 8) = pk;
}

// ------------------------------------------------------------- GEMM 1 (MFMA)
// h1[slot][n][h] = bf16( (agg + (1+eps_e) v) @ W1[e] ), fused BN1 stats.
// Block: 256 thr = 4 waves (wm,wn in 2x2), tile 128(M)x128(N), K-step 16.
__global__ __launch_bounds__(256) void gemm1_mfma(
    const float* __restrict__ agg, const float* __restrict__ v,
    const unsigned short* __restrict__ Bt1, const float* __restrict__ eps,
    unsigned short* __restrict__ h1, float* __restrict__ sum1,
    float* __restrict__ sq1, int e0)
{
  const int slot = blockIdx.y;
  const int e = e0 + slot;
  const int m0 = blockIdx.x * 128;
  const float se = 1.f + eps[e];
  __shared__ unsigned short sA[2048];   // [kh][m][8]
  __shared__ unsigned short sB[2048];   // [kh][n][8]
  __shared__ float ssum[HDIM], ssq[HDIM];
  const int tid = threadIdx.x;
  const int lane = tid & 63, wid = tid >> 6;
  const int wm = wid >> 1, wn = wid & 1;
  const int l31 = lane & 31, half = lane >> 5;
  if (tid < HDIM) { ssum[tid] = 0.f; ssq[tid] = 0.f; }

  floatx16 acc[2][2];
#pragma unroll
  for (int i = 0; i < 2; ++i)
#pragma unroll
    for (int j = 0; j < 2; ++j)
#pragma unroll
      for (int r = 0; r < 16; ++r) acc[i][j][r] = 0.f;

  const int kh = tid >> 7, mm = tid & 127;
  const size_t rowoff = (size_t)(m0 + mm) * CDIM + kh * 8;
  const float* pa = agg + rowoff;
  const float* pv = v + rowoff;
  const unsigned short* btp = Bt1 + (size_t)e * (KS1 * 2048) + tid * 8;

  for (int ks = 0; ks < KS1; ++ks) {
    const int k0 = ks * 16;
    short8 pk;
    if (ks < KS1 - 1 || kh == 0) {        // K=200: tail chunk kh=1 is all-pad
      const float4 a0 = *(const float4*)(pa + k0);
      const float4 a1 = *(const float4*)(pa + k0 + 4);
      const float4 v0 = *(const float4*)(pv + k0);
      const float4 v1 = *(const float4*)(pv + k0 + 4);
      pk[0] = (short)f2bf(fmaf(se, v0.x, a0.x));
      pk[1] = (short)f2bf(fmaf(se, v0.y, a0.y));
      pk[2] = (short)f2bf(fmaf(se, v0.z, a0.z));
      pk[3] = (short)f2bf(fmaf(se, v0.w, a0.w));
      pk[4] = (short)f2bf(fmaf(se, v1.x, a1.x));
      pk[5] = (short)f2bf(fmaf(se, v1.y, a1.y));
      pk[6] = (short)f2bf(fmaf(se, v1.z, a1.z));
      pk[7] = (short)f2bf(fmaf(se, v1.w, a1.w));
    } else {
#pragma unroll
      for (int j = 0; j < 8; ++j) pk[j] = 0;
    }
    *(short8*)(sA + tid * 8) = pk;
    *(short8*)(sB + tid * 8) = *(const short8*)(btp + (size_t)ks * 2048);
    __syncthreads();
    const short8* A8 = (const short8*)sA;
    const short8* B8 = (const short8*)sB;
    short8 af[2], bfr[2];
#pragma unroll
    for (int ms = 0; ms < 2; ++ms)
      af[ms] = A8[half * 128 + wm * 64 + ms * 32 + l31];
#pragma unroll
    for (int ns = 0; ns < 2; ++ns)
      bfr[ns] = B8[half * 128 + wn * 64 + ns * 32 + l31];
#pragma unroll
    for (int ms = 0; ms < 2; ++ms)
#pragma unroll
      for (int ns = 0; ns < 2; ++ns)
        acc[ms][ns] = __builtin_amdgcn_mfma_f32_32x32x16_bf16(
            af[ms], bfr[ns], acc[ms][ns], 0, 0, 0);
    __syncthreads();
  }

#pragma unroll
  for (int ms = 0; ms < 2; ++ms)
#pragma unroll
    for (int ns = 0; ns < 2; ++ns) {
      const int col = wn * 64 + ns * 32 + l31;
      float s = 0.f, q = 0.f;
#pragma unroll
      for (int r = 0; r < 16; ++r) {
        const int row = (r & 3) + 8 * (r >> 2) + 4 * half;
        const int gm = m0 + wm * 64 + ms * 32 + row;
        const float x = acc[ms][ns][r];
        h1[((size_t)slot * NNODES + gm) * HDIM + col] = f2bf(x);
        s += x; q = fmaf(x, x, q);
      }
      atomicAdd(&ssum[col], s);
      atomicAdd(&ssq[col], q);
    }
  __syncthreads();
  if (tid < HDIM) {
    atomicAdd(&sum1[e * HDIM + tid], ssum[tid]);
    atomicAdd(&sq1[e * HDIM + tid], ssq[tid]);
  }
}

// mean/invstd -> affine scale/shift for BN(+g,beta)
__global__ __launch_bounds__(128) void finalize_kernel(
    const float* __restrict__ sum, const float* __restrict__ sq,
    const float* __restrict__ g, const float* __restrict__ beta,
    float* __restrict__ scale, float* __restrict__ shift, int e0)
{
  const int i = (e0 + blockIdx.x) * HDIM + threadIdx.x;
  const float invN = 1.f / (float)NNODES;
  const float mean = sum[i] * invN;
  const float var  = sq[i] * invN - mean * mean;
  const float sc = rsqrtf(var + BNEPS) * g[i];
  scale[i] = sc;
  shift[i] = fmaf(-mean, sc, beta[i]);
}

// ------------------------------------------------------------- GEMM 2 (MFMA)
// h2 = relu(bn1(h1)) @ W2[e]; fused BN2 stats; store only selected rows.
__global__ __launch_bounds__(256) void gemm2_mfma(
    const unsigned short* __restrict__ h1, const unsigned short* __restrict__ Bt2,
    const float* __restrict__ scaleA, const float* __restrict__ shiftA,
    const int* __restrict__ top_idx, float* __restrict__ h2_sel,
    float* __restrict__ sum2, float* __restrict__ sq2, int e0)
{
  const int slot = blockIdx.y;
  const int e = e0 + slot;
  const int m0 = blockIdx.x * 128;
  __shared__ unsigned short sA[2048];
  __shared__ unsigned short sB[2048];
  __shared__ float ssum[HDIM], ssq[HDIM];
  __shared__ int sTop[128];
  const int tid = threadIdx.x;
  const int lane = tid & 63, wid = tid >> 6;
  const int wm = wid >> 1, wn = wid & 1;
  const int l31 = lane & 31, half = lane >> 5;
  if (tid < HDIM) {
    ssum[tid] = 0.f; ssq[tid] = 0.f;
    sTop[tid] = top_idx[m0 + tid];
  }

  floatx16 acc[2][2];
#pragma unroll
  for (int i = 0; i < 2; ++i)
#pragma unroll
    for (int j = 0; j < 2; ++j)
#pragma unroll
      for (int r = 0; r < 16; ++r) acc[i][j][r] = 0.f;

  const int kh = tid >> 7, mm = tid & 127;
  const unsigned short* ph = h1 + ((size_t)slot * NNODES + m0 + mm) * HDIM + kh * 8;
  const float* psc = scaleA + e * HDIM + kh * 8;
  const float* psh = shiftA + e * HDIM + kh * 8;
  const unsigned short* btp = Bt2 + (size_t)e * (KS2 * 2048) + tid * 8;

  for (int ks = 0; ks < KS2; ++ks) {
    const int k0 = ks * 16;
    const short8 hq = *(const short8*)(ph + k0);
    const float4 sc0 = *(const float4*)(psc + k0);
    const float4 sc1 = *(const float4*)(psc + k0 + 4);
    const float4 sh0 = *(const float4*)(psh + k0);
    const float4 sh1 = *(const float4*)(psh + k0 + 4);
    short8 pk;
    pk[0] = (short)f2bf(fmaxf(0.f, fmaf(bf2f((unsigned short)hq[0]), sc0.x, sh0.x)));
    pk[1] = (short)f2bf(fmaxf(0.f, fmaf(bf2f((unsigned short)hq[1]), sc0.y, sh0.y)));
    pk[2] = (short)f2bf(fmaxf(0.f, fmaf(bf2f((unsigned short)hq[2]), sc0.z, sh0.z)));
    pk[3] = (short)f2bf(fmaxf(0.f, fmaf(bf2f((unsigned short)hq[3]), sc0.w, sh0.w)));
    pk[4] = (short)f2bf(fmaxf(0.f, fmaf(bf2f((unsigned short)hq[4]), sc1.x, sh1.x)));
    pk[5] = (short)f2bf(fmaxf(0.f, fmaf(bf2f((unsigned short)hq[5]), sc1.y, sh1.y)));
    pk[6] = (short)f2bf(fmaxf(0.f, fmaf(bf2f((unsigned short)hq[6]), sc1.z, sh1.z)));
    pk[7] = (short)f2bf(fmaxf(0.f, fmaf(bf2f((unsigned short)hq[7]), sc1.w, sh1.w)));
    *(short8*)(sA + tid * 8) = pk;
    *(short8*)(sB + tid * 8) = *(const short8*)(btp + (size_t)ks * 2048);
    __syncthreads();
    const short8* A8 = (const short8*)sA;
    const short8* B8 = (const short8*)sB;
    short8 af[2], bfr[2];
#pragma unroll
    for (int ms = 0; ms < 2; ++ms)
      af[ms] = A8[half * 128 + wm * 64 + ms * 32 + l31];
#pragma unroll
    for (int ns = 0; ns < 2; ++ns)
      bfr[ns] = B8[half * 128 + wn * 64 + ns * 32 + l31];
#pragma unroll
    for (int ms = 0; ms < 2; ++ms)
#pragma unroll
      for (int ns = 0; ns < 2; ++ns)
        acc[ms][ns] = __builtin_amdgcn_mfma_f32_32x32x16_bf16(
            af[ms], bfr[ns], acc[ms][ns], 0, 0, 0);
    __syncthreads();
  }

#pragma unroll
  for (int ms = 0; ms < 2; ++ms)
#pragma unroll
    for (int ns = 0; ns < 2; ++ns) {
      const int col = wn * 64 + ns * 32 + l31;
      float s = 0.f, q = 0.f;
#pragma unroll
      for (int r = 0; r < 16; ++r) {
        const int row = (r & 3) + 8 * (r >> 2) + 4 * half;
        const int ml = wm * 64 + ms * 32 + row;
        const float x = acc[ms][ns][r];
        if (sTop[ml] == e) h2_sel[(size_t)(m0 + ml) * HDIM + col] = x;
        s += x; q = fmaf(x, x, q);
      }
      atomicAdd(&ssum[col], s);
      atomicAdd(&ssq[col], q);
    }
  __syncthreads();
  if (tid < HDIM) {
    atomicAdd(&sum2[e * HDIM + tid], ssum[tid]);
    atomicAdd(&sq2[e * HDIM + tid], ssq[tid]);
  }
}

// --------------------------------------------------------- combine + loss
__global__ __launch_bounds__(256) void combine_kernel(
    const float* __restrict__ h2_sel, const int* __restrict__ top_idx,
    const float* __restrict__ top_val, const float* __restrict__ scale2,
    const float* __restrict__ shift2, float* __restrict__ out)
{
  const int i4 = (blockIdx.x * 256 + threadIdx.x) * 4;
  const int n = i4 >> 7, h = i4 & 127;
  const int e = top_idx[n];
  const float tv = top_val[n];
  const float4 x = *(const float4*)(h2_sel + i4);
  const float* sc = scale2 + e * HDIM + h;
  const float* sh = shift2 + e * HDIM + h;
  float4 o;
  o.x = tv * fmaxf(0.f, fmaf(x.x, sc[0], sh[0]));
  o.y = tv * fmaxf(0.f, fmaf(x.y, sc[1], sh[1]));
  o.z = tv * fmaxf(0.f, fmaf(x.z, sc[2], sh[2]));
  o.w = tv * fmaxf(0.f, fmaf(x.w, sc[3], sh[3]));
  *(float4*)(out + i4) = o;
}

__global__ void loss_kernel(const float* __restrict__ imp,
                            const float* __restrict__ cnt,
                            const float* __restrict__ tv,
                            float* __restrict__ out_losses)
{
  if (threadIdx.x == 0) {
    const float invN = 1.f / (float)NNODES;
    float bal = 0.f;
#pragma unroll
    for (int e = 0; e < NEXP; ++e) bal += (imp[e] * invN) * (cnt[e] * invN);
    out_losses[0] = 0.01f * (float)NEXP * bal;
    out_losses[1] = -0.01f * tv[0] * invN;
  }
}

// ----------------------------------------------------------------- launch
struct WS {
  float *agg, *h2_sel;
  unsigned short *h1, *Bt1, *Bt2;
  int2 *cv;
  int *row_start, *cursors, *top_idx, *incl, *bsum, *boff;
  float *top_val;
  char *zero_base; size_t zero_bytes;
  int *counts;
  float *sum1, *sq1, *sum2, *sq2, *imp, *cnt, *tv;
  float *scaleA, *shiftA, *scale2, *shift2;
  size_t total;
};

static WS carve_ws(char* base, int ecnt, int ne)
{
  WS w; size_t off = 0;
  auto take = [&](size_t b) -> char* {
    char* r = base + off; off += (b + 255) & ~(size_t)255; return r;
  };
  w.agg      = (float*)take((size_t)NNODES * CDIM * 4);
  w.h1       = (unsigned short*)take((size_t)ecnt * NNODES * HDIM * 2);
  w.h2_sel   = (float*)take((size_t)NNODES * HDIM * 4);
  w.cv       = (int2*)take((size_t)ne * 8);
  w.Bt1      = (unsigned short*)take((size_t)NEXP * KS1 * 2048 * 2);
  w.Bt2      = (unsigned short*)take((size_t)NEXP * KS2 * 2048 * 2);
  w.row_start= (int*)take(NNODES * 4);
  w.cursors  = (int*)take(NNODES * 4);
  w.top_idx  = (int*)take(NNODES * 4);
  w.top_val  = (float*)take(NNODES * 4);
  w.incl     = (int*)take(NNODES * 4);
  w.bsum     = (int*)take(64 * 4);
  w.boff     = (int*)take(64 * 4);
  w.zero_base = base + off;
  w.counts = (int*)take(NNODES * 4);
  w.sum1 = (float*)take(NEXP * HDIM * 4);
  w.sq1  = (float*)take(NEXP * HDIM * 4);
  w.sum2 = (float*)take(NEXP * HDIM * 4);
  w.sq2  = (float*)take(NEXP * HDIM * 4);
  w.imp  = (float*)take(NEXP * 4);
  w.cnt  = (float*)take(NEXP * 4);
  w.tv   = (float*)take(4);
  w.zero_bytes = (size_t)((base + off) - w.zero_base);
  w.scaleA = (float*)take(NEXP * HDIM * 4);
  w.shiftA = (float*)take(NEXP * HDIM * 4);
  w.scale2 = (float*)take(NEXP * HDIM * 4);
  w.shift2 = (float*)take(NEXP * HDIM * 4);
  w.total = off;
  return w;
}

extern "C" void kernel_launch(void* const* d_in, const int* in_sizes, int n_in,
                              void* d_out, int out_size, void* d_ws, size_t ws_size,
                              hipStream_t stream)
{
  const float* v      = (const float*)d_in[0];
  const int*   a_rows = (const int*)d_in[1];
  const int*   a_cols = (const int*)d_in[2];
  const float* a_vals = (const float*)d_in[3];
  const float* gate_W = (const float*)d_in[4];
  const float* gate_b = (const float*)d_in[5];
  const float* eps    = (const float*)d_in[6];
  const float* W1     = (const float*)d_in[7];
  const float* g1     = (const float*)d_in[9];
  const float* beta1  = (const float*)d_in[10];
  const float* W2     = (const float*)d_in[11];
  const float* g2     = (const float*)d_in[13];
  const float* beta2  = (const float*)d_in[14];
  const int NE = in_sizes[1];
  float* out = (float*)d_out;
  (void)n_in; (void)out_size;

  int ecnt = NEXP;
  WS w = carve_ws((char*)d_ws, ecnt, NE);
  if (w.total > ws_size) { ecnt = 1; w = carve_ws((char*)d_ws, ecnt, NE); }

  hipMemsetAsync(w.zero_base, 0, w.zero_bytes, stream);

  gating_kernel<<<NNODES / 64, 256, 0, stream>>>(
      v, gate_W, gate_b, w.top_idx, w.top_val, w.imp, w.cnt, w.tv);
  btconv_kernel<<<dim3(KS1, NEXP), 256, 0, stream>>>(W1, w.Bt1, CDIM, KS1);
  btconv_kernel<<<dim3(KS2, NEXP), 256, 0, stream>>>(W2, w.Bt2, HDIM, KS2);
  hist_kernel<<<(NE + 255) / 256, 256, 0, stream>>>(a_rows, w.counts, NE);
  scan_block_kernel<<<NNODES / 1024, 1024, 0, stream>>>(w.counts, w.incl, w.bsum);
  scan_tops_kernel<<<1, 64, 0, stream>>>(w.bsum, w.boff, NNODES / 1024);
  scan_apply_kernel<<<NNODES / 256, 256, 0, stream>>>(
      w.incl, w.boff, w.counts, w.row_start, w.cursors);
  scatter_kernel<<<(NE + 255) / 256, 256, 0, stream>>>(
      a_rows, a_cols, a_vals, w.cursors, w.cv, NE);
  aggregate_kernel<<<NNODES / 4, 256, 0, stream>>>(
      v, w.cv, w.row_start, w.counts, w.agg);

  for (int e0 = 0; e0 < NEXP; e0 += ecnt) {
    dim3 grid(NNODES / 128, ecnt);
    gemm1_mfma<<<grid, 256, 0, stream>>>(
        w.agg, v, w.Bt1, eps, w.h1, w.sum1, w.sq1, e0);
    finalize_kernel<<<ecnt, 128, 0, stream>>>(
        w.sum1, w.sq1, g1, beta1, w.scaleA, w.shiftA, e0);
    gemm2_mfma<<<grid, 256, 0, stream>>>(
        w.h1, w.Bt2, w.scaleA, w.shiftA, w.top_idx,
        w.h2_sel, w.sum2, w.sq2, e0);
    finalize_kernel<<<ecnt, 128, 0, stream>>>(
        w.sum2, w.sq2, g2, beta2, w.scale2, w.shift2, e0);
  }

  combine_kernel<<<(NNODES * HDIM) / 1024, 256, 0, stream>>>(
      w.h2_sel, w.top_idx, w.top_val, w.scale2, w.shift2, out);
  loss_kernel<<<1, 64, 0, stream>>>(w.imp, w.cnt, w.tv, out + (size_t)NNODES * HDIM);
}

// Round 3
// 769.721 us; speedup vs baseline: 2.3026x; 1.0880x over previous
//
#include <hip/hip_runtime.h>

// LayerGIN MoE — round 3:
//  * GEMM1 restructured: A' = [agg ; v] (bf16, K=416) staged ONCE in LDS per
//    64-row block, all 8 experts looped against it with B'_e = [W1 ; se*W1]
//    prebuilt in fragment order (reads ~42MB instead of 472MB).
//  * v/agg kept in bf16 (v_bf conversion fused into gating; aggregate gathers
//    bf16 rows, halving its L2-miss traffic).
//  * h2_sel aliases the dead v_bf/agg_bf region (ws ~163MB).

#define NNODES 51200
#define CDIM   200
#define CPAD   208   // bf16 row padded to 16B multiple
#define HDIM   128
#define NEXP   8
#define BNEPS  1e-5f
#define KC1    26    // K=416 MFMA chunks for A'=[agg;v]
#define KS2    8     // 128/16

typedef __attribute__((ext_vector_type(8)))  short short8;
typedef __attribute__((ext_vector_type(16))) float floatx16;
typedef unsigned short ushort_t;

__device__ __forceinline__ ushort_t f2bf(float x) {
  unsigned int u = __float_as_uint(x);
  u += 0x7fffu + ((u >> 16) & 1u);           // round-to-nearest-even
  return (ushort_t)(u >> 16);
}
__device__ __forceinline__ float bf2f(ushort_t h) {
  return __uint_as_float(((unsigned int)h) << 16);
}

// ------------------------------------------------- gating + v->bf16 convert
__global__ __launch_bounds__(256) void gating_kernel(
    const float* __restrict__ v, const float* __restrict__ gW,
    const float* __restrict__ gb, int* __restrict__ top_idx,
    float* __restrict__ top_val, ushort_t* __restrict__ v_bf,
    float* __restrict__ imp_acc, float* __restrict__ cnt_acc,
    float* __restrict__ tv_acc)
{
  __shared__ float s_imp[NEXP], s_cnt[NEXP], s_tv;
  const int tid = threadIdx.x, lane = tid & 63, wave = tid >> 6;
  if (tid < NEXP) { s_imp[tid] = 0.f; s_cnt[tid] = 0.f; }
  if (tid == 0) s_tv = 0.f;
  __syncthreads();
  const float* g0 = gW + lane * NEXP;
  const float* g1 = gW + (lane + 64) * NEXP;
  const float* g2 = gW + (lane + 128) * NEXP;
  const float* g3 = gW + ((lane < 8) ? (lane + 192) : 199) * NEXP;
  for (int i = 0; i < 16; ++i) {
    const int node = blockIdx.x * 64 + wave * 16 + i;
    const float* vr = v + (size_t)node * CDIM;
    const float x0 = vr[lane];
    const float x1 = vr[lane + 64];
    const float x2 = vr[lane + 128];
    const float x3 = (lane < 8) ? vr[lane + 192] : 0.f;
    ushort_t* vb = v_bf + (size_t)node * CPAD;
    vb[lane]       = f2bf(x0);
    vb[lane + 64]  = f2bf(x1);
    vb[lane + 128] = f2bf(x2);
    if (lane < 16) vb[lane + 192] = (lane < 8) ? f2bf(x3) : (ushort_t)0;
    float p[NEXP];
#pragma unroll
    for (int e = 0; e < NEXP; ++e)
      p[e] = fmaf(x0, g0[e], fmaf(x1, g1[e], fmaf(x2, g2[e], x3 * g3[e])));
#pragma unroll
    for (int off = 32; off > 0; off >>= 1)
#pragma unroll
      for (int e = 0; e < NEXP; ++e) p[e] += __shfl_xor(p[e], off, 64);
#pragma unroll
    for (int e = 0; e < NEXP; ++e) p[e] += gb[e];
    float mx = p[0]; int ai = 0;
#pragma unroll
    for (int e = 1; e < NEXP; ++e) if (p[e] > mx) { mx = p[e]; ai = e; }
    float se = 0.f, pe[NEXP];
#pragma unroll
    for (int e = 0; e < NEXP; ++e) { pe[e] = __expf(p[e] - mx); se += pe[e]; }
    const float inv = 1.f / se;
    if (lane == 0) {
      top_idx[node] = ai;
      top_val[node] = inv;
#pragma unroll
      for (int e = 0; e < NEXP; ++e) atomicAdd(&s_imp[e], pe[e] * inv);
      atomicAdd(&s_cnt[ai], 1.f);
      atomicAdd(&s_tv, inv);
    }
  }
  __syncthreads();
  if (tid < NEXP) { atomicAdd(&imp_acc[tid], s_imp[tid]); atomicAdd(&cnt_acc[tid], s_cnt[tid]); }
  if (tid == 0) atomicAdd(tv_acc, s_tv);
}

// ------------------------------------------------------- CSR build (sort)
__global__ __launch_bounds__(256) void hist_kernel(
    const int* __restrict__ rows, int* __restrict__ counts, int ne)
{
  const int i = blockIdx.x * 256 + threadIdx.x;
  if (i < ne) atomicAdd(&counts[rows[i]], 1);
}

__global__ __launch_bounds__(1024) void scan_block_kernel(
    const int* __restrict__ counts, int* __restrict__ incl, int* __restrict__ bsum)
{
  __shared__ int sh[1024];
  const int tid = threadIdx.x;
  const int idx = blockIdx.x * 1024 + tid;
  sh[tid] = counts[idx];
  __syncthreads();
  for (int off = 1; off < 1024; off <<= 1) {
    const int t = (tid >= off) ? sh[tid - off] : 0;
    __syncthreads();
    sh[tid] += t;
    __syncthreads();
  }
  incl[idx] = sh[tid];
  if (tid == 1023) bsum[blockIdx.x] = sh[tid];
}

__global__ void scan_tops_kernel(const int* __restrict__ bsum,
                                 int* __restrict__ boff, int nb)
{
  const int lane = threadIdx.x;
  const int v = (lane < nb) ? bsum[lane] : 0;
  int incl = v;
#pragma unroll
  for (int off = 1; off < 64; off <<= 1) {
    const int t = __shfl_up(incl, off, 64);
    if (lane >= off) incl += t;
  }
  if (lane < nb) boff[lane] = incl - v;
}

__global__ __launch_bounds__(256) void scan_apply_kernel(
    const int* __restrict__ incl, const int* __restrict__ boff,
    const int* __restrict__ counts, int* __restrict__ row_start,
    int* __restrict__ cursors)
{
  const int i = blockIdx.x * 256 + threadIdx.x;
  const int s = boff[i >> 10] + incl[i] - counts[i];
  row_start[i] = s;
  cursors[i] = s;
}

__global__ __launch_bounds__(256) void scatter_kernel(
    const int* __restrict__ rows, const int* __restrict__ cols,
    const float* __restrict__ vals, int* __restrict__ cursors,
    int2* __restrict__ cv, int ne)
{
  const int i = blockIdx.x * 256 + threadIdx.x;
  if (i < ne) {
    const int pos = atomicAdd(&cursors[rows[i]], 1);
    cv[pos] = make_int2(cols[i], __float_as_int(vals[i]));
  }
}

// one wave per destination node; bf16 gather (8B/lane), 4-edge unroll
__global__ __launch_bounds__(256) void aggregate_kernel(
    const ushort_t* __restrict__ v_bf, const int2* __restrict__ cv,
    const int* __restrict__ row_start, const int* __restrict__ counts,
    ushort_t* __restrict__ agg_bf)
{
  const int node = (blockIdx.x * 256 + threadIdx.x) >> 6;
  const int lane = threadIdx.x & 63;
  const int start = row_start[node];
  const int cnt   = counts[node];
  const bool act  = lane < 52;            // 52 * 4 shorts = 208
  float4 a = make_float4(0.f, 0.f, 0.f, 0.f);
  int k = 0;
  for (; k + 4 <= cnt; k += 4) {
    const int2 e0 = cv[start + k];
    const int2 e1 = cv[start + k + 1];
    const int2 e2 = cv[start + k + 2];
    const int2 e3 = cv[start + k + 3];
    ushort4 x0 = {0,0,0,0}, x1 = {0,0,0,0}, x2 = {0,0,0,0}, x3 = {0,0,0,0};
    if (act) {
      x0 = *(const ushort4*)(v_bf + (size_t)e0.x * CPAD + lane * 4);
      x1 = *(const ushort4*)(v_bf + (size_t)e1.x * CPAD + lane * 4);
      x2 = *(const ushort4*)(v_bf + (size_t)e2.x * CPAD + lane * 4);
      x3 = *(const ushort4*)(v_bf + (size_t)e3.x * CPAD + lane * 4);
    }
    const float v0 = __int_as_float(e0.y), v1 = __int_as_float(e1.y);
    const float v2 = __int_as_float(e2.y), v3 = __int_as_float(e3.y);
    a.x = fmaf(v0, bf2f(x0.x), a.x); a.y = fmaf(v0, bf2f(x0.y), a.y);
    a.z = fmaf(v0, bf2f(x0.z), a.z); a.w = fmaf(v0, bf2f(x0.w), a.w);
    a.x = fmaf(v1, bf2f(x1.x), a.x); a.y = fmaf(v1, bf2f(x1.y), a.y);
    a.z = fmaf(v1, bf2f(x1.z), a.z); a.w = fmaf(v1, bf2f(x1.w), a.w);
    a.x = fmaf(v2, bf2f(x2.x), a.x); a.y = fmaf(v2, bf2f(x2.y), a.y);
    a.z = fmaf(v2, bf2f(x2.z), a.z); a.w = fmaf(v2, bf2f(x2.w), a.w);
    a.x = fmaf(v3, bf2f(x3.x), a.x); a.y = fmaf(v3, bf2f(x3.y), a.y);
    a.z = fmaf(v3, bf2f(x3.z), a.z); a.w = fmaf(v3, bf2f(x3.w), a.w);
  }
  for (; k < cnt; ++k) {
    const int2 e0 = cv[start + k];
    ushort4 x0 = {0,0,0,0};
    if (act) x0 = *(const ushort4*)(v_bf + (size_t)e0.x * CPAD + lane * 4);
    const float v0 = __int_as_float(e0.y);
    a.x = fmaf(v0, bf2f(x0.x), a.x); a.y = fmaf(v0, bf2f(x0.y), a.y);
    a.z = fmaf(v0, bf2f(x0.z), a.z); a.w = fmaf(v0, bf2f(x0.w), a.w);
  }
  if (act) {
    ushort4 o; o.x = f2bf(a.x); o.y = f2bf(a.y); o.z = f2bf(a.z); o.w = f2bf(a.w);
    *(ushort4*)(agg_bf + (size_t)node * CPAD + lane * 4) = o;
  }
}

// ------------------------------- W1 stacked prep: B'_e = [W1_e ; se*W1_e]
// -> Bt1x[e][j(26)][kh(2)][n(128)][8] bf16, zero-padded past K=200 segments
__global__ __launch_bounds__(256) void btconv1x_kernel(
    const float* __restrict__ W1, const float* __restrict__ eps,
    ushort_t* __restrict__ Bt)
{
  const int e = blockIdx.y, j = blockIdx.x;
  const float sc = (j >= 13) ? (1.f + eps[e]) : 1.f;
  const int jj = (j >= 13) ? (j - 13) : j;
  __shared__ float tile[16][128];
  const int tid = threadIdx.x;
  const int kr = tid >> 5, n4 = (tid & 31) * 4;
#pragma unroll
  for (int h = 0; h < 2; ++h) {
    const int k = jj * 16 + kr + h * 8;
    float4 val = make_float4(0.f, 0.f, 0.f, 0.f);
    if (k < CDIM) val = *(const float4*)(W1 + ((size_t)e * CDIM + k) * HDIM + n4);
    *(float4*)&tile[kr + h * 8][n4] = val;
  }
  __syncthreads();
  const int kh = tid >> 7, n = tid & 127;
  short8 pk;
#pragma unroll
  for (int q = 0; q < 8; ++q) pk[q] = (short)f2bf(sc * tile[kh * 8 + q][n]);
  *(short8*)(Bt + (((size_t)e * KC1 + j) * 256 + tid) * 8) = pk;
}

// W2 prep (unchanged): W[e][k][n] fp32 -> Bt[e][ks][kh][n][8] bf16
__global__ __launch_bounds__(256) void btconv_kernel(
    const float* __restrict__ W, ushort_t* __restrict__ Bt, int K, int nks)
{
  const int e = blockIdx.y, ks = blockIdx.x;
  __shared__ float tile[16][128];
  const int tid = threadIdx.x;
  const int kr = tid >> 5, n4 = (tid & 31) * 4;
#pragma unroll
  for (int h = 0; h < 2; ++h) {
    const int k = ks * 16 + kr + h * 8;
    float4 val = make_float4(0.f, 0.f, 0.f, 0.f);
    if (k < K) val = *(const float4*)(W + ((size_t)e * K + k) * HDIM + n4);
    *(float4*)&tile[kr + h * 8][n4] = val;
  }
  __syncthreads();
  const int kh = tid >> 7, n = tid & 127;
  short8 pk;
#pragma unroll
  for (int q = 0; q < 8; ++q) pk[q] = (short)f2bf(tile[kh * 8 + q][n]);
  *(short8*)(Bt + (((size_t)e * nks + ks) * 256 + tid) * 8) = pk;
}

// ---------------------------------------------- GEMM 1 (A'-shared, 8 experts)
// Block: 64 rows, A' (K=416 bf16) staged once in LDS; loop experts, B-frags
// straight from global (L2). h1 bf16 + fused BN1 stats.
__global__ __launch_bounds__(256) void gemm1_mfma(
    const ushort_t* __restrict__ agg_bf, const ushort_t* __restrict__ v_bf,
    const ushort_t* __restrict__ Bt1x, ushort_t* __restrict__ h1,
    float* __restrict__ sum1, float* __restrict__ sq1)
{
  const int m0 = blockIdx.x * 64;
  __shared__ ushort_t sA[52 * 64 * 8];   // [g(52)][m(64)][8] = 53248 B
  __shared__ float ssum[HDIM], ssq[HDIM];
  const int tid = threadIdx.x;
  const int lane = tid & 63, wid = tid >> 6;
  const int wm = wid >> 1, wn = wid & 1;
  const int l31 = lane & 31, half = lane >> 5;

  // stage A' = [agg(26 halves) ; v(26 halves)]
#pragma unroll
  for (int it = 0; it < 13; ++it) {
    const int l = it * 256 + tid;
    const int g = l >> 6, m = l & 63;
    const ushort_t* src = (g < 26)
        ? agg_bf + (size_t)(m0 + m) * CPAD + g * 8
        : v_bf  + (size_t)(m0 + m) * CPAD + (g - 26) * 8;
    *(short8*)(sA + (size_t)l * 8) = *(const short8*)src;
  }
  __syncthreads();

  for (int e = 0; e < NEXP; ++e) {
    if (tid < HDIM) { ssum[tid] = 0.f; ssq[tid] = 0.f; }
    __syncthreads();
    floatx16 acc0, acc1;
#pragma unroll
    for (int r = 0; r < 16; ++r) { acc0[r] = 0.f; acc1[r] = 0.f; }
    const ushort_t* bte = Bt1x + (size_t)e * (KC1 * 2048);
#pragma unroll
    for (int j = 0; j < KC1; ++j) {
      const short8 af = *(const short8*)(sA + (size_t)((2 * j + half) * 64 + wm * 32 + l31) * 8);
      const short8 b0 = *(const short8*)(bte + (size_t)j * 2048 + (size_t)(half * 128 + wn * 64 + l31) * 8);
      const short8 b1 = *(const short8*)(bte + (size_t)j * 2048 + (size_t)(half * 128 + wn * 64 + 32 + l31) * 8);
      acc0 = __builtin_amdgcn_mfma_f32_32x32x16_bf16(af, b0, acc0, 0, 0, 0);
      acc1 = __builtin_amdgcn_mfma_f32_32x32x16_bf16(af, b1, acc1, 0, 0, 0);
    }
    ushort_t* h1e = h1 + (size_t)e * NNODES * HDIM;
#pragma unroll
    for (int ns = 0; ns < 2; ++ns) {
      const floatx16& a = ns ? acc1 : acc0;
      const int col = wn * 64 + ns * 32 + l31;
      float s = 0.f, q = 0.f;
#pragma unroll
      for (int r = 0; r < 16; ++r) {
        const int row = (r & 3) + 8 * (r >> 2) + 4 * half;
        const float x = a[r];
        h1e[(size_t)(m0 + wm * 32 + row) * HDIM + col] = f2bf(x);
        s += x; q = fmaf(x, x, q);
      }
      atomicAdd(&ssum[col], s);
      atomicAdd(&ssq[col], q);
    }
    __syncthreads();
    if (tid < HDIM) {
      atomicAdd(&sum1[e * HDIM + tid], ssum[tid]);
      atomicAdd(&sq1[e * HDIM + tid], ssq[tid]);
    }
  }
}

// mean/invstd -> affine scale/shift for BN(+g,beta)
__global__ __launch_bounds__(128) void finalize_kernel(
    const float* __restrict__ sum, const float* __restrict__ sq,
    const float* __restrict__ g, const float* __restrict__ beta,
    float* __restrict__ scale, float* __restrict__ shift)
{
  const int i = blockIdx.x * HDIM + threadIdx.x;
  const float invN = 1.f / (float)NNODES;
  const float mean = sum[i] * invN;
  const float var  = sq[i] * invN - mean * mean;
  const float sc = rsqrtf(var + BNEPS) * g[i];
  scale[i] = sc;
  shift[i] = fmaf(-mean, sc, beta[i]);
}

// ------------------------------------------------------------- GEMM 2 (MFMA)
__global__ __launch_bounds__(256) void gemm2_mfma(
    const ushort_t* __restrict__ h1, const ushort_t* __restrict__ Bt2,
    const float* __restrict__ scaleA, const float* __restrict__ shiftA,
    const int* __restrict__ top_idx, float* __restrict__ h2_sel,
    float* __restrict__ sum2, float* __restrict__ sq2)
{
  const int e = blockIdx.y;
  const int m0 = blockIdx.x * 128;
  __shared__ ushort_t sA[2048];
  __shared__ ushort_t sB[2048];
  __shared__ float ssum[HDIM], ssq[HDIM];
  __shared__ int sTop[128];
  const int tid = threadIdx.x;
  const int lane = tid & 63, wid = tid >> 6;
  const int wm = wid >> 1, wn = wid & 1;
  const int l31 = lane & 31, half = lane >> 5;
  if (tid < HDIM) {
    ssum[tid] = 0.f; ssq[tid] = 0.f;
    sTop[tid] = top_idx[m0 + tid];
  }

  floatx16 acc[2][2];
#pragma unroll
  for (int i = 0; i < 2; ++i)
#pragma unroll
    for (int j = 0; j < 2; ++j)
#pragma unroll
      for (int r = 0; r < 16; ++r) acc[i][j][r] = 0.f;

  const int kh = tid >> 7, mm = tid & 127;
  const ushort_t* ph = h1 + ((size_t)e * NNODES + m0 + mm) * HDIM + kh * 8;
  const float* psc = scaleA + e * HDIM + kh * 8;
  const float* psh = shiftA + e * HDIM + kh * 8;
  const ushort_t* btp = Bt2 + (size_t)e * (KS2 * 2048) + tid * 8;

  for (int ks = 0; ks < KS2; ++ks) {
    const int k0 = ks * 16;
    const short8 hq = *(const short8*)(ph + k0);
    const float4 sc0 = *(const float4*)(psc + k0);
    const float4 sc1 = *(const float4*)(psc + k0 + 4);
    const float4 sh0 = *(const float4*)(psh + k0);
    const float4 sh1 = *(const float4*)(psh + k0 + 4);
    short8 pk;
    pk[0] = (short)f2bf(fmaxf(0.f, fmaf(bf2f((ushort_t)hq[0]), sc0.x, sh0.x)));
    pk[1] = (short)f2bf(fmaxf(0.f, fmaf(bf2f((ushort_t)hq[1]), sc0.y, sh0.y)));
    pk[2] = (short)f2bf(fmaxf(0.f, fmaf(bf2f((ushort_t)hq[2]), sc0.z, sh0.z)));
    pk[3] = (short)f2bf(fmaxf(0.f, fmaf(bf2f((ushort_t)hq[3]), sc0.w, sh0.w)));
    pk[4] = (short)f2bf(fmaxf(0.f, fmaf(bf2f((ushort_t)hq[4]), sc1.x, sh1.x)));
    pk[5] = (short)f2bf(fmaxf(0.f, fmaf(bf2f((ushort_t)hq[5]), sc1.y, sh1.y)));
    pk[6] = (short)f2bf(fmaxf(0.f, fmaf(bf2f((ushort_t)hq[6]), sc1.z, sh1.z)));
    pk[7] = (short)f2bf(fmaxf(0.f, fmaf(bf2f((ushort_t)hq[7]), sc1.w, sh1.w)));
    *(short8*)(sA + tid * 8) = pk;
    *(short8*)(sB + tid * 8) = *(const short8*)(btp + (size_t)ks * 2048);
    __syncthreads();
    const short8* A8 = (const short8*)sA;
    const short8* B8 = (const short8*)sB;
    short8 af[2], bfr[2];
#pragma unroll
    for (int ms = 0; ms < 2; ++ms)
      af[ms] = A8[half * 128 + wm * 64 + ms * 32 + l31];
#pragma unroll
    for (int ns = 0; ns < 2; ++ns)
      bfr[ns] = B8[half * 128 + wn * 64 + ns * 32 + l31];
#pragma unroll
    for (int ms = 0; ms < 2; ++ms)
#pragma unroll
      for (int ns = 0; ns < 2; ++ns)
        acc[ms][ns] = __builtin_amdgcn_mfma_f32_32x32x16_bf16(
            af[ms], bfr[ns], acc[ms][ns], 0, 0, 0);
    __syncthreads();
  }

#pragma unroll
  for (int ms = 0; ms < 2; ++ms)
#pragma unroll
    for (int ns = 0; ns < 2; ++ns) {
      const int col = wn * 64 + ns * 32 + l31;
      float s = 0.f, q = 0.f;
#pragma unroll
      for (int r = 0; r < 16; ++r) {
        const int row = (r & 3) + 8 * (r >> 2) + 4 * half;
        const int ml = wm * 64 + ms * 32 + row;
        const float x = acc[ms][ns][r];
        if (sTop[ml] == e) h2_sel[(size_t)(m0 + ml) * HDIM + col] = x;
        s += x; q = fmaf(x, x, q);
      }
      atomicAdd(&ssum[col], s);
      atomicAdd(&ssq[col], q);
    }
  __syncthreads();
  if (tid < HDIM) {
    atomicAdd(&sum2[e * HDIM + tid], ssum[tid]);
    atomicAdd(&sq2[e * HDIM + tid], ssq[tid]);
  }
}

// --------------------------------------------------------- combine + loss
__global__ __launch_bounds__(256) void combine_kernel(
    const float* __restrict__ h2_sel, const int* __restrict__ top_idx,
    const float* __restrict__ top_val, const float* __restrict__ scale2,
    const float* __restrict__ shift2, float* __restrict__ out)
{
  const int i4 = (blockIdx.x * 256 + threadIdx.x) * 4;
  const int n = i4 >> 7, h = i4 & 127;
  const int e = top_idx[n];
  const float tv = top_val[n];
  const float4 x = *(const float4*)(h2_sel + i4);
  const float* sc = scale2 + e * HDIM + h;
  const float* sh = shift2 + e * HDIM + h;
  float4 o;
  o.x = tv * fmaxf(0.f, fmaf(x.x, sc[0], sh[0]));
  o.y = tv * fmaxf(0.f, fmaf(x.y, sc[1], sh[1]));
  o.z = tv * fmaxf(0.f, fmaf(x.z, sc[2], sh[2]));
  o.w = tv * fmaxf(0.f, fmaf(x.w, sc[3], sh[3]));
  *(float4*)(out + i4) = o;
}

__global__ void loss_kernel(const float* __restrict__ imp,
                            const float* __restrict__ cnt,
                            const float* __restrict__ tv,
                            float* __restrict__ out_losses)
{
  if (threadIdx.x == 0) {
    const float invN = 1.f / (float)NNODES;
    float bal = 0.f;
#pragma unroll
    for (int e = 0; e < NEXP; ++e) bal += (imp[e] * invN) * (cnt[e] * invN);
    out_losses[0] = 0.01f * (float)NEXP * bal;
    out_losses[1] = -0.01f * tv[0] * invN;
  }
}

// ----------------------------------------------------------------- launch
struct WS {
  ushort_t *v_bf, *agg_bf, *h1, *Bt1x, *Bt2;
  float *h2_sel;     // aliases v_bf/agg_bf region (dead after gemm1)
  int2 *cv;
  int *row_start, *cursors, *top_idx, *incl, *bsum, *boff;
  float *top_val;
  char *zero_base; size_t zero_bytes;
  int *counts;
  float *sum1, *sq1, *sum2, *sq2, *imp, *cnt, *tv;
  float *scaleA, *shiftA, *scale2, *shift2;
  size_t total;
};

static WS carve_ws(char* base, int ne)
{
  WS w; size_t off = 0;
  auto take = [&](size_t b) -> char* {
    char* r = base + off; off += (b + 255) & ~(size_t)255; return r;
  };
  w.v_bf   = (ushort_t*)take((size_t)NNODES * CPAD * 2);
  w.agg_bf = (ushort_t*)take((size_t)NNODES * CPAD * 2);
  w.h2_sel = (float*)w.v_bf;   // 26.2MB alias inside 42.6MB dead region
  w.h1     = (ushort_t*)take((size_t)NEXP * NNODES * HDIM * 2);
  w.cv     = (int2*)take((size_t)ne * 8);
  w.Bt1x   = (ushort_t*)take((size_t)NEXP * KC1 * 2048 * 2);
  w.Bt2    = (ushort_t*)take((size_t)NEXP * KS2 * 2048 * 2);
  w.row_start= (int*)take(NNODES * 4);
  w.cursors  = (int*)take(NNODES * 4);
  w.top_idx  = (int*)take(NNODES * 4);
  w.top_val  = (float*)take(NNODES * 4);
  w.incl     = (int*)take(NNODES * 4);
  w.bsum     = (int*)take(64 * 4);
  w.boff     = (int*)take(64 * 4);
  w.zero_base = base + off;
  w.counts = (int*)take(NNODES * 4);
  w.sum1 = (float*)take(NEXP * HDIM * 4);
  w.sq1  = (float*)take(NEXP * HDIM * 4);
  w.sum2 = (float*)take(NEXP * HDIM * 4);
  w.sq2  = (float*)take(NEXP * HDIM * 4);
  w.imp  = (float*)take(NEXP * 4);
  w.cnt  = (float*)take(NEXP * 4);
  w.tv   = (float*)take(4);
  w.zero_bytes = (size_t)((base + off) - w.zero_base);
  w.scaleA = (float*)take(NEXP * HDIM * 4);
  w.shiftA = (float*)take(NEXP * HDIM * 4);
  w.scale2 = (float*)take(NEXP * HDIM * 4);
  w.shift2 = (float*)take(NEXP * HDIM * 4);
  w.total = off;
  return w;
}

extern "C" void kernel_launch(void* const* d_in, const int* in_sizes, int n_in,
                              void* d_out, int out_size, void* d_ws, size_t ws_size,
                              hipStream_t stream)
{
  const float* v      = (const float*)d_in[0];
  const int*   a_rows = (const int*)d_in[1];
  const int*   a_cols = (const int*)d_in[2];
  const float* a_vals = (const float*)d_in[3];
  const float* gate_W = (const float*)d_in[4];
  const float* gate_b = (const float*)d_in[5];
  const float* eps    = (const float*)d_in[6];
  const float* W1     = (const float*)d_in[7];
  const float* g1     = (const float*)d_in[9];
  const float* beta1  = (const float*)d_in[10];
  const float* W2     = (const float*)d_in[11];
  const float* g2     = (const float*)d_in[13];
  const float* beta2  = (const float*)d_in[14];
  const int NE = in_sizes[1];
  float* out = (float*)d_out;
  (void)n_in; (void)out_size; (void)ws_size;

  WS w = carve_ws((char*)d_ws, NE);

  hipMemsetAsync(w.zero_base, 0, w.zero_bytes, stream);

  gating_kernel<<<NNODES / 64, 256, 0, stream>>>(
      v, gate_W, gate_b, w.top_idx, w.top_val, w.v_bf, w.imp, w.cnt, w.tv);
  btconv1x_kernel<<<dim3(KC1, NEXP), 256, 0, stream>>>(W1, eps, w.Bt1x);
  btconv_kernel<<<dim3(KS2, NEXP), 256, 0, stream>>>(W2, w.Bt2, HDIM, KS2);
  hist_kernel<<<(NE + 255) / 256, 256, 0, stream>>>(a_rows, w.counts, NE);
  scan_block_kernel<<<NNODES / 1024, 1024, 0, stream>>>(w.counts, w.incl, w.bsum);
  scan_tops_kernel<<<1, 64, 0, stream>>>(w.bsum, w.boff, NNODES / 1024);
  scan_apply_kernel<<<NNODES / 256, 256, 0, stream>>>(
      w.incl, w.boff, w.counts, w.row_start, w.cursors);
  scatter_kernel<<<(NE + 255) / 256, 256, 0, stream>>>(
      a_rows, a_cols, a_vals, w.cursors, w.cv, NE);
  aggregate_kernel<<<NNODES / 4, 256, 0, stream>>>(
      w.v_bf, w.cv, w.row_start, w.counts, w.agg_bf);

  gemm1_mfma<<<NNODES / 64, 256, 0, stream>>>(
      w.agg_bf, w.v_bf, w.Bt1x, w.h1, w.sum1, w.sq1);
  finalize_kernel<<<NEXP, 128, 0, stream>>>(
      w.sum1, w.sq1, g1, beta1, w.scaleA, w.shiftA);
  gemm2_mfma<<<dim3(NNODES / 128, NEXP), 256, 0, stream>>>(
      w.h1, w.Bt2, w.scaleA, w.shiftA, w.top_idx, w.h2_sel, w.sum2, w.sq2);
  finalize_kernel<<<NEXP, 128, 0, stream>>>(
      w.sum2, w.sq2, g2, beta2, w.scale2, w.shift2);

  combine_kernel<<<(NNODES * HDIM) / 1024, 256, 0, stream>>>(
      w.h2_sel, w.top_idx, w.top_val, w.scale2, w.shift2, out);
  loss_kernel<<<1, 64, 0, stream>>>(w.imp, w.cnt, w.tv, out + (size_t)NNODES * HDIM);
}

// Round 4
// 664.730 us; speedup vs baseline: 2.6663x; 1.1579x over previous
//
#include <hip/hip_runtime.h>

// LayerGIN MoE — round 4: barrier-free GEMM K-loops.
//  * GEMM1: A'=[agg;v] (K=416 bf16) staged once; each wave owns 2 experts and
//    the full 128-col width (8 MFMA per 4 B-loads, 1-chunk prefetch). BN stats
//    via LDS atomics, single end barrier. No per-expert barriers.
//  * GEMM2: full-K transformed A staged once in LDS (pad-129, coalesced
//    loads), 8-step unrolled MFMA sweep, one barrier total.

#define NNODES 51200
#define CDIM   200
#define CPAD   208
#define HDIM   128
#define NEXP   8
#define BNEPS  1e-5f
#define KC1    26    // K=416 chunks of 16 for A'=[agg;v]
#define KS2    8     // 128/16

typedef __attribute__((ext_vector_type(8)))  short short8;
typedef __attribute__((ext_vector_type(16))) float floatx16;
typedef unsigned short ushort_t;

__device__ __forceinline__ ushort_t f2bf(float x) {
  unsigned int u = __float_as_uint(x);
  u += 0x7fffu + ((u >> 16) & 1u);
  return (ushort_t)(u >> 16);
}
__device__ __forceinline__ float bf2f(ushort_t h) {
  return __uint_as_float(((unsigned int)h) << 16);
}

// ------------------------------------------------- gating + v->bf16 convert
__global__ __launch_bounds__(256) void gating_kernel(
    const float* __restrict__ v, const float* __restrict__ gW,
    const float* __restrict__ gb, int* __restrict__ top_idx,
    float* __restrict__ top_val, ushort_t* __restrict__ v_bf,
    float* __restrict__ imp_acc, float* __restrict__ cnt_acc,
    float* __restrict__ tv_acc)
{
  __shared__ float s_imp[NEXP], s_cnt[NEXP], s_tv;
  const int tid = threadIdx.x, lane = tid & 63, wave = tid >> 6;
  if (tid < NEXP) { s_imp[tid] = 0.f; s_cnt[tid] = 0.f; }
  if (tid == 0) s_tv = 0.f;
  __syncthreads();
  const float* g0 = gW + lane * NEXP;
  const float* g1 = gW + (lane + 64) * NEXP;
  const float* g2 = gW + (lane + 128) * NEXP;
  const float* g3 = gW + ((lane < 8) ? (lane + 192) : 199) * NEXP;
  for (int i = 0; i < 16; ++i) {
    const int node = blockIdx.x * 64 + wave * 16 + i;
    const float* vr = v + (size_t)node * CDIM;
    const float x0 = vr[lane];
    const float x1 = vr[lane + 64];
    const float x2 = vr[lane + 128];
    const float x3 = (lane < 8) ? vr[lane + 192] : 0.f;
    ushort_t* vb = v_bf + (size_t)node * CPAD;
    vb[lane]       = f2bf(x0);
    vb[lane + 64]  = f2bf(x1);
    vb[lane + 128] = f2bf(x2);
    if (lane < 16) vb[lane + 192] = (lane < 8) ? f2bf(x3) : (ushort_t)0;
    float p[NEXP];
#pragma unroll
    for (int e = 0; e < NEXP; ++e)
      p[e] = fmaf(x0, g0[e], fmaf(x1, g1[e], fmaf(x2, g2[e], x3 * g3[e])));
#pragma unroll
    for (int off = 32; off > 0; off >>= 1)
#pragma unroll
      for (int e = 0; e < NEXP; ++e) p[e] += __shfl_xor(p[e], off, 64);
#pragma unroll
    for (int e = 0; e < NEXP; ++e) p[e] += gb[e];
    float mx = p[0]; int ai = 0;
#pragma unroll
    for (int e = 1; e < NEXP; ++e) if (p[e] > mx) { mx = p[e]; ai = e; }
    float se = 0.f, pe[NEXP];
#pragma unroll
    for (int e = 0; e < NEXP; ++e) { pe[e] = __expf(p[e] - mx); se += pe[e]; }
    const float inv = 1.f / se;
    if (lane == 0) {
      top_idx[node] = ai;
      top_val[node] = inv;
#pragma unroll
      for (int e = 0; e < NEXP; ++e) atomicAdd(&s_imp[e], pe[e] * inv);
      atomicAdd(&s_cnt[ai], 1.f);
      atomicAdd(&s_tv, inv);
    }
  }
  __syncthreads();
  if (tid < NEXP) { atomicAdd(&imp_acc[tid], s_imp[tid]); atomicAdd(&cnt_acc[tid], s_cnt[tid]); }
  if (tid == 0) atomicAdd(tv_acc, s_tv);
}

// ------------------------------------------------------- CSR build (sort)
__global__ __launch_bounds__(256) void hist_kernel(
    const int* __restrict__ rows, int* __restrict__ counts, int ne)
{
  const int i = blockIdx.x * 256 + threadIdx.x;
  if (i < ne) atomicAdd(&counts[rows[i]], 1);
}

__global__ __launch_bounds__(1024) void scan_block_kernel(
    const int* __restrict__ counts, int* __restrict__ incl, int* __restrict__ bsum)
{
  __shared__ int sh[1024];
  const int tid = threadIdx.x;
  const int idx = blockIdx.x * 1024 + tid;
  sh[tid] = counts[idx];
  __syncthreads();
  for (int off = 1; off < 1024; off <<= 1) {
    const int t = (tid >= off) ? sh[tid - off] : 0;
    __syncthreads();
    sh[tid] += t;
    __syncthreads();
  }
  incl[idx] = sh[tid];
  if (tid == 1023) bsum[blockIdx.x] = sh[tid];
}

__global__ void scan_tops_kernel(const int* __restrict__ bsum,
                                 int* __restrict__ boff, int nb)
{
  const int lane = threadIdx.x;
  const int v = (lane < nb) ? bsum[lane] : 0;
  int incl = v;
#pragma unroll
  for (int off = 1; off < 64; off <<= 1) {
    const int t = __shfl_up(incl, off, 64);
    if (lane >= off) incl += t;
  }
  if (lane < nb) boff[lane] = incl - v;
}

__global__ __launch_bounds__(256) void scan_apply_kernel(
    const int* __restrict__ incl, const int* __restrict__ boff,
    const int* __restrict__ counts, int* __restrict__ row_start,
    int* __restrict__ cursors)
{
  const int i = blockIdx.x * 256 + threadIdx.x;
  const int s = boff[i >> 10] + incl[i] - counts[i];
  row_start[i] = s;
  cursors[i] = s;
}

__global__ __launch_bounds__(256) void scatter_kernel(
    const int* __restrict__ rows, const int* __restrict__ cols,
    const float* __restrict__ vals, int* __restrict__ cursors,
    int2* __restrict__ cv, int ne)
{
  const int i = blockIdx.x * 256 + threadIdx.x;
  if (i < ne) {
    const int pos = atomicAdd(&cursors[rows[i]], 1);
    cv[pos] = make_int2(cols[i], __float_as_int(vals[i]));
  }
}

// one wave per destination node; bf16 gather (8B/lane), 4-edge unroll
__global__ __launch_bounds__(256) void aggregate_kernel(
    const ushort_t* __restrict__ v_bf, const int2* __restrict__ cv,
    const int* __restrict__ row_start, const int* __restrict__ counts,
    ushort_t* __restrict__ agg_bf)
{
  const int node = (blockIdx.x * 256 + threadIdx.x) >> 6;
  const int lane = threadIdx.x & 63;
  const int start = row_start[node];
  const int cnt   = counts[node];
  const bool act  = lane < 52;
  float4 a = make_float4(0.f, 0.f, 0.f, 0.f);
  int k = 0;
  for (; k + 4 <= cnt; k += 4) {
    const int2 e0 = cv[start + k];
    const int2 e1 = cv[start + k + 1];
    const int2 e2 = cv[start + k + 2];
    const int2 e3 = cv[start + k + 3];
    ushort4 x0 = {0,0,0,0}, x1 = {0,0,0,0}, x2 = {0,0,0,0}, x3 = {0,0,0,0};
    if (act) {
      x0 = *(const ushort4*)(v_bf + (size_t)e0.x * CPAD + lane * 4);
      x1 = *(const ushort4*)(v_bf + (size_t)e1.x * CPAD + lane * 4);
      x2 = *(const ushort4*)(v_bf + (size_t)e2.x * CPAD + lane * 4);
      x3 = *(const ushort4*)(v_bf + (size_t)e3.x * CPAD + lane * 4);
    }
    const float v0 = __int_as_float(e0.y), v1 = __int_as_float(e1.y);
    const float v2 = __int_as_float(e2.y), v3 = __int_as_float(e3.y);
    a.x = fmaf(v0, bf2f(x0.x), a.x); a.y = fmaf(v0, bf2f(x0.y), a.y);
    a.z = fmaf(v0, bf2f(x0.z), a.z); a.w = fmaf(v0, bf2f(x0.w), a.w);
    a.x = fmaf(v1, bf2f(x1.x), a.x); a.y = fmaf(v1, bf2f(x1.y), a.y);
    a.z = fmaf(v1, bf2f(x1.z), a.z); a.w = fmaf(v1, bf2f(x1.w), a.w);
    a.x = fmaf(v2, bf2f(x2.x), a.x); a.y = fmaf(v2, bf2f(x2.y), a.y);
    a.z = fmaf(v2, bf2f(x2.z), a.z); a.w = fmaf(v2, bf2f(x2.w), a.w);
    a.x = fmaf(v3, bf2f(x3.x), a.x); a.y = fmaf(v3, bf2f(x3.y), a.y);
    a.z = fmaf(v3, bf2f(x3.z), a.z); a.w = fmaf(v3, bf2f(x3.w), a.w);
  }
  for (; k < cnt; ++k) {
    const int2 e0 = cv[start + k];
    ushort4 x0 = {0,0,0,0};
    if (act) x0 = *(const ushort4*)(v_bf + (size_t)e0.x * CPAD + lane * 4);
    const float v0 = __int_as_float(e0.y);
    a.x = fmaf(v0, bf2f(x0.x), a.x); a.y = fmaf(v0, bf2f(x0.y), a.y);
    a.z = fmaf(v0, bf2f(x0.z), a.z); a.w = fmaf(v0, bf2f(x0.w), a.w);
  }
  if (act) {
    ushort4 o; o.x = f2bf(a.x); o.y = f2bf(a.y); o.z = f2bf(a.z); o.w = f2bf(a.w);
    *(ushort4*)(agg_bf + (size_t)node * CPAD + lane * 4) = o;
  }
}

// ------------------------------- W1 stacked prep: B'_e = [W1_e ; se*W1_e]
__global__ __launch_bounds__(256) void btconv1x_kernel(
    const float* __restrict__ W1, const float* __restrict__ eps,
    ushort_t* __restrict__ Bt)
{
  const int e = blockIdx.y, j = blockIdx.x;
  const float sc = (j >= 13) ? (1.f + eps[e]) : 1.f;
  const int jj = (j >= 13) ? (j - 13) : j;
  __shared__ float tile[16][128];
  const int tid = threadIdx.x;
  const int kr = tid >> 5, n4 = (tid & 31) * 4;
#pragma unroll
  for (int h = 0; h < 2; ++h) {
    const int k = jj * 16 + kr + h * 8;
    float4 val = make_float4(0.f, 0.f, 0.f, 0.f);
    if (k < CDIM) val = *(const float4*)(W1 + ((size_t)e * CDIM + k) * HDIM + n4);
    *(float4*)&tile[kr + h * 8][n4] = val;
  }
  __syncthreads();
  const int kh = tid >> 7, n = tid & 127;
  short8 pk;
#pragma unroll
  for (int q = 0; q < 8; ++q) pk[q] = (short)f2bf(sc * tile[kh * 8 + q][n]);
  *(short8*)(Bt + (((size_t)e * KC1 + j) * 256 + tid) * 8) = pk;
}

// W2 prep: W[e][k][n] fp32 -> Bt[e][ks][kh][n][8] bf16
__global__ __launch_bounds__(256) void btconv_kernel(
    const float* __restrict__ W, ushort_t* __restrict__ Bt, int K, int nks)
{
  const int e = blockIdx.y, ks = blockIdx.x;
  __shared__ float tile[16][128];
  const int tid = threadIdx.x;
  const int kr = tid >> 5, n4 = (tid & 31) * 4;
#pragma unroll
  for (int h = 0; h < 2; ++h) {
    const int k = ks * 16 + kr + h * 8;
    float4 val = make_float4(0.f, 0.f, 0.f, 0.f);
    if (k < K) val = *(const float4*)(W + ((size_t)e * K + k) * HDIM + n4);
    *(float4*)&tile[kr + h * 8][n4] = val;
  }
  __syncthreads();
  const int kh = tid >> 7, n = tid & 127;
  short8 pk;
#pragma unroll
  for (int q = 0; q < 8; ++q) pk[q] = (short)f2bf(tile[kh * 8 + q][n]);
  *(short8*)(Bt + (((size_t)e * nks + ks) * 256 + tid) * 8) = pk;
}

// ---------------------------------------------- GEMM 1: wave-per-expert-pair
// 256 thr / 4 waves; A' (64 rows x K=416) in LDS; wave w computes experts
// {w, w+4} over all 128 cols. No barriers in the hot loops.
__global__ __launch_bounds__(256, 2) void gemm1_mfma(
    const ushort_t* __restrict__ agg_bf, const ushort_t* __restrict__ v_bf,
    const ushort_t* __restrict__ Bt1x, ushort_t* __restrict__ h1,
    float* __restrict__ sum1, float* __restrict__ sq1)
{
  const int m0 = blockIdx.x * 64;
  __shared__ ushort_t sA[52 * 64 * 8];       // 53248 B
  __shared__ float ssum[NEXP][HDIM];         // 4096 B
  __shared__ float ssq[NEXP][HDIM];          // 4096 B
  const int tid = threadIdx.x;
  const int lane = tid & 63, wid = tid >> 6;
  const int l31 = lane & 31, half = lane >> 5;

  {
    float* z = &ssum[0][0];
    float* z2 = &ssq[0][0];
#pragma unroll
    for (int t = 0; t < 4; ++t) { z[t * 256 + tid] = 0.f; z2[t * 256 + tid] = 0.f; }
  }
#pragma unroll
  for (int it = 0; it < 13; ++it) {
    const int l = it * 256 + tid;
    const int g = l >> 6, m = l & 63;
    const ushort_t* src = (g < 26)
        ? agg_bf + (size_t)(m0 + m) * CPAD + g * 8
        : v_bf  + (size_t)(m0 + m) * CPAD + (g - 26) * 8;
    *(short8*)(sA + (size_t)l * 8) = *(const short8*)src;
  }
  __syncthreads();

#pragma unroll
  for (int ei = 0; ei < 2; ++ei) {
    const int e = wid + ei * 4;
    floatx16 acc[2][4];
#pragma unroll
    for (int ms = 0; ms < 2; ++ms)
#pragma unroll
      for (int ns = 0; ns < 4; ++ns)
#pragma unroll
        for (int r = 0; r < 16; ++r) acc[ms][ns][r] = 0.f;

    const ushort_t* bte = Bt1x + ((size_t)e * KC1 * 256 + half * 128 + l31) * 8;
    short8 nb[4];
#pragma unroll
    for (int ns = 0; ns < 4; ++ns)
      nb[ns] = *(const short8*)(bte + (size_t)(ns * 32) * 8);
#pragma unroll
    for (int j = 0; j < KC1; ++j) {
      short8 b[4];
#pragma unroll
      for (int ns = 0; ns < 4; ++ns) b[ns] = nb[ns];
      if (j < KC1 - 1) {
#pragma unroll
        for (int ns = 0; ns < 4; ++ns)
          nb[ns] = *(const short8*)(bte + (size_t)((j + 1) * 256 + ns * 32) * 8);
      }
      short8 a[2];
#pragma unroll
      for (int ms = 0; ms < 2; ++ms)
        a[ms] = *(const short8*)(sA + (size_t)((2 * j + half) * 64 + ms * 32 + l31) * 8);
#pragma unroll
      for (int ms = 0; ms < 2; ++ms)
#pragma unroll
        for (int ns = 0; ns < 4; ++ns)
          acc[ms][ns] = __builtin_amdgcn_mfma_f32_32x32x16_bf16(
              a[ms], b[ns], acc[ms][ns], 0, 0, 0);
    }

    ushort_t* h1e = h1 + ((size_t)e * NNODES + m0) * HDIM;
#pragma unroll
    for (int ns = 0; ns < 4; ++ns) {
      const int col = ns * 32 + l31;
#pragma unroll
      for (int ms = 0; ms < 2; ++ms) {
        float s = 0.f, q = 0.f;
#pragma unroll
        for (int r = 0; r < 16; ++r) {
          const int row = ms * 32 + (r & 3) + 8 * (r >> 2) + 4 * half;
          const float x = acc[ms][ns][r];
          h1e[(size_t)row * HDIM + col] = f2bf(x);
          s += x; q = fmaf(x, x, q);
        }
        atomicAdd(&ssum[e][col], s);
        atomicAdd(&ssq[e][col], q);
      }
    }
  }
  __syncthreads();
  {
    const float* zs = &ssum[0][0];
    const float* zq = &ssq[0][0];
#pragma unroll
    for (int t = 0; t < 4; ++t) {
      atomicAdd(&sum1[t * 256 + tid], zs[t * 256 + tid]);
      atomicAdd(&sq1[t * 256 + tid], zq[t * 256 + tid]);
    }
  }
}

// mean/invstd -> affine scale/shift for BN(+g,beta)
__global__ __launch_bounds__(128) void finalize_kernel(
    const float* __restrict__ sum, const float* __restrict__ sq,
    const float* __restrict__ g, const float* __restrict__ beta,
    float* __restrict__ scale, float* __restrict__ shift)
{
  const int i = blockIdx.x * HDIM + threadIdx.x;
  const float invN = 1.f / (float)NNODES;
  const float mean = sum[i] * invN;
  const float var  = sq[i] * invN - mean * mean;
  const float sc = rsqrtf(var + BNEPS) * g[i];
  scale[i] = sc;
  shift[i] = fmaf(-mean, sc, beta[i]);
}

// ---------------------------------- GEMM 2: single-barrier full-K A staging
// 128-row tile; A = relu(bn1(h1)) transformed during staging (coalesced
// 256B/row loads, per-thread constant scale/shift); pad-129 LDS layout.
__global__ __launch_bounds__(256, 4) void gemm2_mfma(
    const ushort_t* __restrict__ h1, const ushort_t* __restrict__ Bt2,
    const float* __restrict__ scaleA, const float* __restrict__ shiftA,
    const int* __restrict__ top_idx, float* __restrict__ h2_sel,
    float* __restrict__ sum2, float* __restrict__ sq2)
{
  const int e = blockIdx.y;
  const int m0 = blockIdx.x * 128;
  __shared__ ushort_t sA[16 * 129 * 8];     // 33024 B, slot = g*129 + m
  __shared__ float ssum[HDIM], ssq[HDIM];
  __shared__ int sTop[128];
  const int tid = threadIdx.x;
  const int lane = tid & 63, wid = tid >> 6;
  const int wm = wid >> 1, wn = wid & 1;
  const int l31 = lane & 31, half = lane >> 5;
  if (tid < HDIM) {
    ssum[tid] = 0.f; ssq[tid] = 0.f;
    sTop[tid] = top_idx[m0 + tid];
  }
  // stage + transform: thread covers k-group g=tid&15 for rows r0, r0+16, ...
  {
    const int g = tid & 15, r0 = tid >> 4;
    const float4 sc0 = *(const float4*)(scaleA + e * HDIM + g * 8);
    const float4 sc1 = *(const float4*)(scaleA + e * HDIM + g * 8 + 4);
    const float4 sh0 = *(const float4*)(shiftA + e * HDIM + g * 8);
    const float4 sh1 = *(const float4*)(shiftA + e * HDIM + g * 8 + 4);
#pragma unroll
    for (int c = 0; c < 8; ++c) {
      const int m = c * 16 + r0;
      const short8 hq = *(const short8*)(
          h1 + ((size_t)e * NNODES + m0 + m) * HDIM + g * 8);
      short8 pk;
      pk[0] = (short)f2bf(fmaxf(0.f, fmaf(bf2f((ushort_t)hq[0]), sc0.x, sh0.x)));
      pk[1] = (short)f2bf(fmaxf(0.f, fmaf(bf2f((ushort_t)hq[1]), sc0.y, sh0.y)));
      pk[2] = (short)f2bf(fmaxf(0.f, fmaf(bf2f((ushort_t)hq[2]), sc0.z, sh0.z)));
      pk[3] = (short)f2bf(fmaxf(0.f, fmaf(bf2f((ushort_t)hq[3]), sc0.w, sh0.w)));
      pk[4] = (short)f2bf(fmaxf(0.f, fmaf(bf2f((ushort_t)hq[4]), sc1.x, sh1.x)));
      pk[5] = (short)f2bf(fmaxf(0.f, fmaf(bf2f((ushort_t)hq[5]), sc1.y, sh1.y)));
      pk[6] = (short)f2bf(fmaxf(0.f, fmaf(bf2f((ushort_t)hq[6]), sc1.z, sh1.z)));
      pk[7] = (short)f2bf(fmaxf(0.f, fmaf(bf2f((ushort_t)hq[7]), sc1.w, sh1.w)));
      *(short8*)(sA + (size_t)(g * 129 + m) * 8) = pk;
    }
  }
  __syncthreads();

  floatx16 acc[2][2];
#pragma unroll
  for (int i = 0; i < 2; ++i)
#pragma unroll
    for (int j = 0; j < 2; ++j)
#pragma unroll
      for (int r = 0; r < 16; ++r) acc[i][j][r] = 0.f;

  const ushort_t* bte = Bt2 + ((size_t)e * KS2 * 256 + half * 128 + wn * 64 + l31) * 8;
  short8 nb0 = *(const short8*)(bte);
  short8 nb1 = *(const short8*)(bte + 32 * 8);
#pragma unroll
  for (int ks = 0; ks < KS2; ++ks) {
    const short8 b0 = nb0, b1 = nb1;
    if (ks < KS2 - 1) {
      nb0 = *(const short8*)(bte + (size_t)((ks + 1) * 256) * 8);
      nb1 = *(const short8*)(bte + (size_t)((ks + 1) * 256 + 32) * 8);
    }
    const short8 a0 = *(const short8*)(sA + (size_t)((2 * ks + half) * 129 + wm * 64 + l31) * 8);
    const short8 a1 = *(const short8*)(sA + (size_t)((2 * ks + half) * 129 + wm * 64 + 32 + l31) * 8);
    acc[0][0] = __builtin_amdgcn_mfma_f32_32x32x16_bf16(a0, b0, acc[0][0], 0, 0, 0);
    acc[0][1] = __builtin_amdgcn_mfma_f32_32x32x16_bf16(a0, b1, acc[0][1], 0, 0, 0);
    acc[1][0] = __builtin_amdgcn_mfma_f32_32x32x16_bf16(a1, b0, acc[1][0], 0, 0, 0);
    acc[1][1] = __builtin_amdgcn_mfma_f32_32x32x16_bf16(a1, b1, acc[1][1], 0, 0, 0);
  }

#pragma unroll
  for (int ms = 0; ms < 2; ++ms)
#pragma unroll
    for (int ns = 0; ns < 2; ++ns) {
      const int col = wn * 64 + ns * 32 + l31;
      float s = 0.f, q = 0.f;
#pragma unroll
      for (int r = 0; r < 16; ++r) {
        const int row = wm * 64 + ms * 32 + (r & 3) + 8 * (r >> 2) + 4 * half;
        const float x = acc[ms][ns][r];
        if (sTop[row] == e) h2_sel[(size_t)(m0 + row) * HDIM + col] = x;
        s += x; q = fmaf(x, x, q);
      }
      atomicAdd(&ssum[col], s);
      atomicAdd(&ssq[col], q);
    }
  __syncthreads();
  if (tid < HDIM) atomicAdd(&sum2[e * HDIM + tid], ssum[tid]);
  else            atomicAdd(&sq2[e * HDIM + tid - HDIM], ssq[tid - HDIM]);
}

// --------------------------------------------------------- combine + loss
__global__ __launch_bounds__(256) void combine_kernel(
    const float* __restrict__ h2_sel, const int* __restrict__ top_idx,
    const float* __restrict__ top_val, const float* __restrict__ scale2,
    const float* __restrict__ shift2, float* __restrict__ out)
{
  const int i4 = (blockIdx.x * 256 + threadIdx.x) * 4;
  const int n = i4 >> 7, h = i4 & 127;
  const int e = top_idx[n];
  const float tv = top_val[n];
  const float4 x = *(const float4*)(h2_sel + i4);
  const float* sc = scale2 + e * HDIM + h;
  const float* sh = shift2 + e * HDIM + h;
  float4 o;
  o.x = tv * fmaxf(0.f, fmaf(x.x, sc[0], sh[0]));
  o.y = tv * fmaxf(0.f, fmaf(x.y, sc[1], sh[1]));
  o.z = tv * fmaxf(0.f, fmaf(x.z, sc[2], sh[2]));
  o.w = tv * fmaxf(0.f, fmaf(x.w, sc[3], sh[3]));
  *(float4*)(out + i4) = o;
}

__global__ void loss_kernel(const float* __restrict__ imp,
                            const float* __restrict__ cnt,
                            const float* __restrict__ tv,
                            float* __restrict__ out_losses)
{
  if (threadIdx.x == 0) {
    const float invN = 1.f / (float)NNODES;
    float bal = 0.f;
#pragma unroll
    for (int e = 0; e < NEXP; ++e) bal += (imp[e] * invN) * (cnt[e] * invN);
    out_losses[0] = 0.01f * (float)NEXP * bal;
    out_losses[1] = -0.01f * tv[0] * invN;
  }
}

// ----------------------------------------------------------------- launch
struct WS {
  ushort_t *v_bf, *agg_bf, *h1, *Bt1x, *Bt2;
  float *h2_sel;
  int2 *cv;
  int *row_start, *cursors, *top_idx, *incl, *bsum, *boff;
  float *top_val;
  char *zero_base; size_t zero_bytes;
  int *counts;
  float *sum1, *sq1, *sum2, *sq2, *imp, *cnt, *tv;
  float *scaleA, *shiftA, *scale2, *shift2;
  size_t total;
};

static WS carve_ws(char* base, int ne)
{
  WS w; size_t off = 0;
  auto take = [&](size_t b) -> char* {
    char* r = base + off; off += (b + 255) & ~(size_t)255; return r;
  };
  w.v_bf   = (ushort_t*)take((size_t)NNODES * CPAD * 2);
  w.agg_bf = (ushort_t*)take((size_t)NNODES * CPAD * 2);
  w.h2_sel = (float*)w.v_bf;
  w.h1     = (ushort_t*)take((size_t)NEXP * NNODES * HDIM * 2);
  w.cv     = (int2*)take((size_t)ne * 8);
  w.Bt1x   = (ushort_t*)take((size_t)NEXP * KC1 * 2048 * 2);
  w.Bt2    = (ushort_t*)take((size_t)NEXP * KS2 * 2048 * 2);
  w.row_start= (int*)take(NNODES * 4);
  w.cursors  = (int*)take(NNODES * 4);
  w.top_idx  = (int*)take(NNODES * 4);
  w.top_val  = (float*)take(NNODES * 4);
  w.incl     = (int*)take(NNODES * 4);
  w.bsum     = (int*)take(64 * 4);
  w.boff     = (int*)take(64 * 4);
  w.zero_base = base + off;
  w.counts = (int*)take(NNODES * 4);
  w.sum1 = (float*)take(NEXP * HDIM * 4);
  w.sq1  = (float*)take(NEXP * HDIM * 4);
  w.sum2 = (float*)take(NEXP * HDIM * 4);
  w.sq2  = (float*)take(NEXP * HDIM * 4);
  w.imp  = (float*)take(NEXP * 4);
  w.cnt  = (float*)take(NEXP * 4);
  w.tv   = (float*)take(4);
  w.zero_bytes = (size_t)((base + off) - w.zero_base);
  w.scaleA = (float*)take(NEXP * HDIM * 4);
  w.shiftA = (float*)take(NEXP * HDIM * 4);
  w.scale2 = (float*)take(NEXP * HDIM * 4);
  w.shift2 = (float*)take(NEXP * HDIM * 4);
  w.total = off;
  return w;
}

extern "C" void kernel_launch(void* const* d_in, const int* in_sizes, int n_in,
                              void* d_out, int out_size, void* d_ws, size_t ws_size,
                              hipStream_t stream)
{
  const float* v      = (const float*)d_in[0];
  const int*   a_rows = (const int*)d_in[1];
  const int*   a_cols = (const int*)d_in[2];
  const float* a_vals = (const float*)d_in[3];
  const float* gate_W = (const float*)d_in[4];
  const float* gate_b = (const float*)d_in[5];
  const float* eps    = (const float*)d_in[6];
  const float* W1     = (const float*)d_in[7];
  const float* g1     = (const float*)d_in[9];
  const float* beta1  = (const float*)d_in[10];
  const float* W2     = (const float*)d_in[11];
  const float* g2     = (const float*)d_in[13];
  const float* beta2  = (const float*)d_in[14];
  const int NE = in_sizes[1];
  float* out = (float*)d_out;
  (void)n_in; (void)out_size; (void)ws_size;

  WS w = carve_ws((char*)d_ws, NE);

  hipMemsetAsync(w.zero_base, 0, w.zero_bytes, stream);

  gating_kernel<<<NNODES / 64, 256, 0, stream>>>(
      v, gate_W, gate_b, w.top_idx, w.top_val, w.v_bf, w.imp, w.cnt, w.tv);
  btconv1x_kernel<<<dim3(KC1, NEXP), 256, 0, stream>>>(W1, eps, w.Bt1x);
  btconv_kernel<<<dim3(KS2, NEXP), 256, 0, stream>>>(W2, w.Bt2, HDIM, KS2);
  hist_kernel<<<(NE + 255) / 256, 256, 0, stream>>>(a_rows, w.counts, NE);
  scan_block_kernel<<<NNODES / 1024, 1024, 0, stream>>>(w.counts, w.incl, w.bsum);
  scan_tops_kernel<<<1, 64, 0, stream>>>(w.bsum, w.boff, NNODES / 1024);
  scan_apply_kernel<<<NNODES / 256, 256, 0, stream>>>(
      w.incl, w.boff, w.counts, w.row_start, w.cursors);
  scatter_kernel<<<(NE + 255) / 256, 256, 0, stream>>>(
      a_rows, a_cols, a_vals, w.cursors, w.cv, NE);
  aggregate_kernel<<<NNODES / 4, 256, 0, stream>>>(
      w.v_bf, w.cv, w.row_start, w.counts, w.agg_bf);

  gemm1_mfma<<<NNODES / 64, 256, 0, stream>>>(
      w.agg_bf, w.v_bf, w.Bt1x, w.h1, w.sum1, w.sq1);
  finalize_kernel<<<NEXP, 128, 0, stream>>>(
      w.sum1, w.sq1, g1, beta1, w.scaleA, w.shiftA);
  gemm2_mfma<<<dim3(NNODES / 128, NEXP), 256, 0, stream>>>(
      w.h1, w.Bt2, w.scaleA, w.shiftA, w.top_idx, w.h2_sel, w.sum2, w.sq2);
  finalize_kernel<<<NEXP, 128, 0, stream>>>(
      w.sum2, w.sq2, g2, beta2, w.scale2, w.shift2);

  combine_kernel<<<(NNODES * HDIM) / 1024, 256, 0, stream>>>(
      w.h2_sel, w.top_idx, w.top_val, w.scale2, w.shift2, out);
  loss_kernel<<<1, 64, 0, stream>>>(w.imp, w.cnt, w.tv, out + (size_t)NNODES * HDIM);
}

// Round 5
// 637.561 us; speedup vs baseline: 2.7799x; 1.0426x over previous
//
#include <hip/hip_runtime.h>

// LayerGIN MoE — round 5: two-pass bucketed edge scatter (kills the 8x
// line-granularity write amplification of the random 8B scatter).
//  Pass A: 400 buckets (row>>7), per-block LDS histogram + ranged reservation,
//          packed (row<<16|col, val) written in ~164B runs (~1.3x ampl).
//  Pass B: one block per bucket, scatters within a ~32KB cv window (~1.0x).
// GEMMs unchanged from round 4 (barrier-free K-loops, wave-per-expert-pair).

#define NNODES 51200
#define CDIM   200
#define CPAD   208
#define HDIM   128
#define NEXP   8
#define BNEPS  1e-5f
#define KC1    26    // K=416 chunks of 16 for A'=[agg;v]
#define KS2    8     // 128/16
#define NB     400   // scatter buckets (128 rows each)
#define EPB    8192  // edges per block, pass A

typedef __attribute__((ext_vector_type(8)))  short short8;
typedef __attribute__((ext_vector_type(16))) float floatx16;
typedef unsigned short ushort_t;

__device__ __forceinline__ ushort_t f2bf(float x) {
  unsigned int u = __float_as_uint(x);
  u += 0x7fffu + ((u >> 16) & 1u);
  return (ushort_t)(u >> 16);
}
__device__ __forceinline__ float bf2f(ushort_t h) {
  return __uint_as_float(((unsigned int)h) << 16);
}

// ------------------------------------------------- gating + v->bf16 convert
__global__ __launch_bounds__(256) void gating_kernel(
    const float* __restrict__ v, const float* __restrict__ gW,
    const float* __restrict__ gb, int* __restrict__ top_idx,
    float* __restrict__ top_val, ushort_t* __restrict__ v_bf,
    float* __restrict__ imp_acc, float* __restrict__ cnt_acc,
    float* __restrict__ tv_acc)
{
  __shared__ float s_imp[NEXP], s_cnt[NEXP], s_tv;
  const int tid = threadIdx.x, lane = tid & 63, wave = tid >> 6;
  if (tid < NEXP) { s_imp[tid] = 0.f; s_cnt[tid] = 0.f; }
  if (tid == 0) s_tv = 0.f;
  __syncthreads();
  const float* g0 = gW + lane * NEXP;
  const float* g1 = gW + (lane + 64) * NEXP;
  const float* g2 = gW + (lane + 128) * NEXP;
  const float* g3 = gW + ((lane < 8) ? (lane + 192) : 199) * NEXP;
  for (int i = 0; i < 16; ++i) {
    const int node = blockIdx.x * 64 + wave * 16 + i;
    const float* vr = v + (size_t)node * CDIM;
    const float x0 = vr[lane];
    const float x1 = vr[lane + 64];
    const float x2 = vr[lane + 128];
    const float x3 = (lane < 8) ? vr[lane + 192] : 0.f;
    ushort_t* vb = v_bf + (size_t)node * CPAD;
    vb[lane]       = f2bf(x0);
    vb[lane + 64]  = f2bf(x1);
    vb[lane + 128] = f2bf(x2);
    if (lane < 16) vb[lane + 192] = (lane < 8) ? f2bf(x3) : (ushort_t)0;
    float p[NEXP];
#pragma unroll
    for (int e = 0; e < NEXP; ++e)
      p[e] = fmaf(x0, g0[e], fmaf(x1, g1[e], fmaf(x2, g2[e], x3 * g3[e])));
#pragma unroll
    for (int off = 32; off > 0; off >>= 1)
#pragma unroll
      for (int e = 0; e < NEXP; ++e) p[e] += __shfl_xor(p[e], off, 64);
#pragma unroll
    for (int e = 0; e < NEXP; ++e) p[e] += gb[e];
    float mx = p[0]; int ai = 0;
#pragma unroll
    for (int e = 1; e < NEXP; ++e) if (p[e] > mx) { mx = p[e]; ai = e; }
    float se = 0.f, pe[NEXP];
#pragma unroll
    for (int e = 0; e < NEXP; ++e) { pe[e] = __expf(p[e] - mx); se += pe[e]; }
    const float inv = 1.f / se;
    if (lane == 0) {
      top_idx[node] = ai;
      top_val[node] = inv;
#pragma unroll
      for (int e = 0; e < NEXP; ++e) atomicAdd(&s_imp[e], pe[e] * inv);
      atomicAdd(&s_cnt[ai], 1.f);
      atomicAdd(&s_tv, inv);
    }
  }
  __syncthreads();
  if (tid < NEXP) { atomicAdd(&imp_acc[tid], s_imp[tid]); atomicAdd(&cnt_acc[tid], s_cnt[tid]); }
  if (tid == 0) atomicAdd(tv_acc, s_tv);
}

// ------------------------------------------------------- CSR build (sort)
__global__ __launch_bounds__(256) void hist_kernel(
    const int* __restrict__ rows, int* __restrict__ counts, int ne)
{
  const int i = blockIdx.x * 256 + threadIdx.x;
  if (i < ne) atomicAdd(&counts[rows[i]], 1);
}

__global__ __launch_bounds__(1024) void scan_block_kernel(
    const int* __restrict__ counts, int* __restrict__ incl, int* __restrict__ bsum)
{
  __shared__ int sh[1024];
  const int tid = threadIdx.x;
  const int idx = blockIdx.x * 1024 + tid;
  sh[tid] = counts[idx];
  __syncthreads();
  for (int off = 1; off < 1024; off <<= 1) {
    const int t = (tid >= off) ? sh[tid - off] : 0;
    __syncthreads();
    sh[tid] += t;
    __syncthreads();
  }
  incl[idx] = sh[tid];
  if (tid == 1023) bsum[blockIdx.x] = sh[tid];
}

__global__ void scan_tops_kernel(const int* __restrict__ bsum,
                                 int* __restrict__ boff, int nb)
{
  const int lane = threadIdx.x;
  const int v = (lane < nb) ? bsum[lane] : 0;
  int incl = v;
#pragma unroll
  for (int off = 1; off < 64; off <<= 1) {
    const int t = __shfl_up(incl, off, 64);
    if (lane >= off) incl += t;
  }
  if (lane < nb) boff[lane] = incl - v;
}

__global__ __launch_bounds__(256) void scan_apply_kernel(
    const int* __restrict__ incl, const int* __restrict__ boff,
    const int* __restrict__ counts, int* __restrict__ row_start,
    int* __restrict__ cursors, int* __restrict__ cursA)
{
  const int i = blockIdx.x * 256 + threadIdx.x;
  const int s = boff[i >> 10] + incl[i] - counts[i];
  row_start[i] = s;
  cursors[i] = s;
  if ((i & 127) == 0) cursA[i >> 7] = s;   // bucket base = row_start[128b]
}

// ---- pass A: coarse bucket scatter, packed (row<<16|col, val) ----
__global__ __launch_bounds__(256) void bucketA_kernel(
    const int* __restrict__ rows, const int* __restrict__ cols,
    const float* __restrict__ vals, int* __restrict__ cursA,
    int2* __restrict__ tmp, int ne)
{
  __shared__ int cnt[NB];
  __shared__ int gbase[NB];
  const int tid = threadIdx.x;
  const int base = blockIdx.x * EPB;
  for (int b = tid; b < NB; b += 256) cnt[b] = 0;
  __syncthreads();
#pragma unroll 4
  for (int j = 0; j < EPB / 256; ++j) {
    const int i = base + j * 256 + tid;
    if (i < ne) atomicAdd(&cnt[rows[i] >> 7], 1);
  }
  __syncthreads();
  for (int b = tid; b < NB; b += 256) {
    const int c = cnt[b];
    gbase[b] = c ? atomicAdd(&cursA[b], c) : 0;
    cnt[b] = 0;
  }
  __syncthreads();
#pragma unroll 4
  for (int j = 0; j < EPB / 256; ++j) {
    const int i = base + j * 256 + tid;
    if (i < ne) {
      const int r = rows[i];
      const int b = r >> 7;
      const int pos = gbase[b] + atomicAdd(&cnt[b], 1);
      tmp[pos] = make_int2((r << 16) | cols[i], __float_as_int(vals[i]));
    }
  }
}

// ---- pass B: fine scatter within one bucket's ~32KB cv window ----
__global__ __launch_bounds__(256) void bucketB_kernel(
    const int2* __restrict__ tmp, const int* __restrict__ row_start,
    int* __restrict__ cursors, int2* __restrict__ cv, int ne)
{
  const int b = blockIdx.x;
  const int s = row_start[b << 7];
  const int epos = (b == NB - 1) ? ne : row_start[(b + 1) << 7];
  for (int i = s + threadIdx.x; i < epos; i += 256) {
    const int2 t = tmp[i];
    const int r = (int)(((unsigned int)t.x) >> 16);
    const int pos = atomicAdd(&cursors[r], 1);
    cv[pos] = make_int2(t.x & 0xffff, t.y);
  }
}

// one wave per destination node; bf16 gather (8B/lane), 4-edge unroll
__global__ __launch_bounds__(256) void aggregate_kernel(
    const ushort_t* __restrict__ v_bf, const int2* __restrict__ cv,
    const int* __restrict__ row_start, const int* __restrict__ counts,
    ushort_t* __restrict__ agg_bf)
{
  const int node = (blockIdx.x * 256 + threadIdx.x) >> 6;
  const int lane = threadIdx.x & 63;
  const int start = row_start[node];
  const int cnt   = counts[node];
  const bool act  = lane < 52;
  float4 a = make_float4(0.f, 0.f, 0.f, 0.f);
  int k = 0;
  for (; k + 4 <= cnt; k += 4) {
    const int2 e0 = cv[start + k];
    const int2 e1 = cv[start + k + 1];
    const int2 e2 = cv[start + k + 2];
    const int2 e3 = cv[start + k + 3];
    ushort4 x0 = {0,0,0,0}, x1 = {0,0,0,0}, x2 = {0,0,0,0}, x3 = {0,0,0,0};
    if (act) {
      x0 = *(const ushort4*)(v_bf + (size_t)e0.x * CPAD + lane * 4);
      x1 = *(const ushort4*)(v_bf + (size_t)e1.x * CPAD + lane * 4);
      x2 = *(const ushort4*)(v_bf + (size_t)e2.x * CPAD + lane * 4);
      x3 = *(const ushort4*)(v_bf + (size_t)e3.x * CPAD + lane * 4);
    }
    const float v0 = __int_as_float(e0.y), v1 = __int_as_float(e1.y);
    const float v2 = __int_as_float(e2.y), v3 = __int_as_float(e3.y);
    a.x = fmaf(v0, bf2f(x0.x), a.x); a.y = fmaf(v0, bf2f(x0.y), a.y);
    a.z = fmaf(v0, bf2f(x0.z), a.z); a.w = fmaf(v0, bf2f(x0.w), a.w);
    a.x = fmaf(v1, bf2f(x1.x), a.x); a.y = fmaf(v1, bf2f(x1.y), a.y);
    a.z = fmaf(v1, bf2f(x1.z), a.z); a.w = fmaf(v1, bf2f(x1.w), a.w);
    a.x = fmaf(v2, bf2f(x2.x), a.x); a.y = fmaf(v2, bf2f(x2.y), a.y);
    a.z = fmaf(v2, bf2f(x2.z), a.z); a.w = fmaf(v2, bf2f(x2.w), a.w);
    a.x = fmaf(v3, bf2f(x3.x), a.x); a.y = fmaf(v3, bf2f(x3.y), a.y);
    a.z = fmaf(v3, bf2f(x3.z), a.z); a.w = fmaf(v3, bf2f(x3.w), a.w);
  }
  for (; k < cnt; ++k) {
    const int2 e0 = cv[start + k];
    ushort4 x0 = {0,0,0,0};
    if (act) x0 = *(const ushort4*)(v_bf + (size_t)e0.x * CPAD + lane * 4);
    const float v0 = __int_as_float(e0.y);
    a.x = fmaf(v0, bf2f(x0.x), a.x); a.y = fmaf(v0, bf2f(x0.y), a.y);
    a.z = fmaf(v0, bf2f(x0.z), a.z); a.w = fmaf(v0, bf2f(x0.w), a.w);
  }
  if (act) {
    ushort4 o; o.x = f2bf(a.x); o.y = f2bf(a.y); o.z = f2bf(a.z); o.w = f2bf(a.w);
    *(ushort4*)(agg_bf + (size_t)node * CPAD + lane * 4) = o;
  }
}

// ------------------------------- W1 stacked prep: B'_e = [W1_e ; se*W1_e]
__global__ __launch_bounds__(256) void btconv1x_kernel(
    const float* __restrict__ W1, const float* __restrict__ eps,
    ushort_t* __restrict__ Bt)
{
  const int e = blockIdx.y, j = blockIdx.x;
  const float sc = (j >= 13) ? (1.f + eps[e]) : 1.f;
  const int jj = (j >= 13) ? (j - 13) : j;
  __shared__ float tile[16][128];
  const int tid = threadIdx.x;
  const int kr = tid >> 5, n4 = (tid & 31) * 4;
#pragma unroll
  for (int h = 0; h < 2; ++h) {
    const int k = jj * 16 + kr + h * 8;
    float4 val = make_float4(0.f, 0.f, 0.f, 0.f);
    if (k < CDIM) val = *(const float4*)(W1 + ((size_t)e * CDIM + k) * HDIM + n4);
    *(float4*)&tile[kr + h * 8][n4] = val;
  }
  __syncthreads();
  const int kh = tid >> 7, n = tid & 127;
  short8 pk;
#pragma unroll
  for (int q = 0; q < 8; ++q) pk[q] = (short)f2bf(sc * tile[kh * 8 + q][n]);
  *(short8*)(Bt + (((size_t)e * KC1 + j) * 256 + tid) * 8) = pk;
}

// W2 prep: W[e][k][n] fp32 -> Bt[e][ks][kh][n][8] bf16
__global__ __launch_bounds__(256) void btconv_kernel(
    const float* __restrict__ W, ushort_t* __restrict__ Bt, int K, int nks)
{
  const int e = blockIdx.y, ks = blockIdx.x;
  __shared__ float tile[16][128];
  const int tid = threadIdx.x;
  const int kr = tid >> 5, n4 = (tid & 31) * 4;
#pragma unroll
  for (int h = 0; h < 2; ++h) {
    const int k = ks * 16 + kr + h * 8;
    float4 val = make_float4(0.f, 0.f, 0.f, 0.f);
    if (k < K) val = *(const float4*)(W + ((size_t)e * K + k) * HDIM + n4);
    *(float4*)&tile[kr + h * 8][n4] = val;
  }
  __syncthreads();
  const int kh = tid >> 7, n = tid & 127;
  short8 pk;
#pragma unroll
  for (int q = 0; q < 8; ++q) pk[q] = (short)f2bf(tile[kh * 8 + q][n]);
  *(short8*)(Bt + (((size_t)e * nks + ks) * 256 + tid) * 8) = pk;
}

// ---------------------------------------------- GEMM 1: wave-per-expert-pair
__global__ __launch_bounds__(256, 2) void gemm1_mfma(
    const ushort_t* __restrict__ agg_bf, const ushort_t* __restrict__ v_bf,
    const ushort_t* __restrict__ Bt1x, ushort_t* __restrict__ h1,
    float* __restrict__ sum1, float* __restrict__ sq1)
{
  const int m0 = blockIdx.x * 64;
  __shared__ ushort_t sA[52 * 64 * 8];       // 53248 B
  __shared__ float ssum[NEXP][HDIM];
  __shared__ float ssq[NEXP][HDIM];
  const int tid = threadIdx.x;
  const int lane = tid & 63, wid = tid >> 6;
  const int l31 = lane & 31, half = lane >> 5;

  {
    float* z = &ssum[0][0];
    float* z2 = &ssq[0][0];
#pragma unroll
    for (int t = 0; t < 4; ++t) { z[t * 256 + tid] = 0.f; z2[t * 256 + tid] = 0.f; }
  }
#pragma unroll
  for (int it = 0; it < 13; ++it) {
    const int l = it * 256 + tid;
    const int g = l >> 6, m = l & 63;
    const ushort_t* src = (g < 26)
        ? agg_bf + (size_t)(m0 + m) * CPAD + g * 8
        : v_bf  + (size_t)(m0 + m) * CPAD + (g - 26) * 8;
    *(short8*)(sA + (size_t)l * 8) = *(const short8*)src;
  }
  __syncthreads();

#pragma unroll
  for (int ei = 0; ei < 2; ++ei) {
    const int e = wid + ei * 4;
    floatx16 acc[2][4];
#pragma unroll
    for (int ms = 0; ms < 2; ++ms)
#pragma unroll
      for (int ns = 0; ns < 4; ++ns)
#pragma unroll
        for (int r = 0; r < 16; ++r) acc[ms][ns][r] = 0.f;

    const ushort_t* bte = Bt1x + ((size_t)e * KC1 * 256 + half * 128 + l31) * 8;
    short8 nb[4];
#pragma unroll
    for (int ns = 0; ns < 4; ++ns)
      nb[ns] = *(const short8*)(bte + (size_t)(ns * 32) * 8);
#pragma unroll
    for (int j = 0; j < KC1; ++j) {
      short8 b[4];
#pragma unroll
      for (int ns = 0; ns < 4; ++ns) b[ns] = nb[ns];
      if (j < KC1 - 1) {
#pragma unroll
        for (int ns = 0; ns < 4; ++ns)
          nb[ns] = *(const short8*)(bte + (size_t)((j + 1) * 256 + ns * 32) * 8);
      }
      short8 a[2];
#pragma unroll
      for (int ms = 0; ms < 2; ++ms)
        a[ms] = *(const short8*)(sA + (size_t)((2 * j + half) * 64 + ms * 32 + l31) * 8);
#pragma unroll
      for (int ms = 0; ms < 2; ++ms)
#pragma unroll
        for (int ns = 0; ns < 4; ++ns)
          acc[ms][ns] = __builtin_amdgcn_mfma_f32_32x32x16_bf16(
              a[ms], b[ns], acc[ms][ns], 0, 0, 0);
    }

    ushort_t* h1e = h1 + ((size_t)e * NNODES + m0) * HDIM;
#pragma unroll
    for (int ns = 0; ns < 4; ++ns) {
      const int col = ns * 32 + l31;
#pragma unroll
      for (int ms = 0; ms < 2; ++ms) {
        float s = 0.f, q = 0.f;
#pragma unroll
        for (int r = 0; r < 16; ++r) {
          const int row = ms * 32 + (r & 3) + 8 * (r >> 2) + 4 * half;
          const float x = acc[ms][ns][r];
          h1e[(size_t)row * HDIM + col] = f2bf(x);
          s += x; q = fmaf(x, x, q);
        }
        atomicAdd(&ssum[e][col], s);
        atomicAdd(&ssq[e][col], q);
      }
    }
  }
  __syncthreads();
  {
    const float* zs = &ssum[0][0];
    const float* zq = &ssq[0][0];
#pragma unroll
    for (int t = 0; t < 4; ++t) {
      atomicAdd(&sum1[t * 256 + tid], zs[t * 256 + tid]);
      atomicAdd(&sq1[t * 256 + tid], zq[t * 256 + tid]);
    }
  }
}

// mean/invstd -> affine scale/shift for BN(+g,beta)
__global__ __launch_bounds__(128) void finalize_kernel(
    const float* __restrict__ sum, const float* __restrict__ sq,
    const float* __restrict__ g, const float* __restrict__ beta,
    float* __restrict__ scale, float* __restrict__ shift)
{
  const int i = blockIdx.x * HDIM + threadIdx.x;
  const float invN = 1.f / (float)NNODES;
  const float mean = sum[i] * invN;
  const float var  = sq[i] * invN - mean * mean;
  const float sc = rsqrtf(var + BNEPS) * g[i];
  scale[i] = sc;
  shift[i] = fmaf(-mean, sc, beta[i]);
}

// ---------------------------------- GEMM 2: single-barrier full-K A staging
__global__ __launch_bounds__(256, 4) void gemm2_mfma(
    const ushort_t* __restrict__ h1, const ushort_t* __restrict__ Bt2,
    const float* __restrict__ scaleA, const float* __restrict__ shiftA,
    const int* __restrict__ top_idx, float* __restrict__ h2_sel,
    float* __restrict__ sum2, float* __restrict__ sq2)
{
  const int e = blockIdx.y;
  const int m0 = blockIdx.x * 128;
  __shared__ ushort_t sA[16 * 129 * 8];     // 33024 B
  __shared__ float ssum[HDIM], ssq[HDIM];
  __shared__ int sTop[128];
  const int tid = threadIdx.x;
  const int lane = tid & 63, wid = tid >> 6;
  const int wm = wid >> 1, wn = wid & 1;
  const int l31 = lane & 31, half = lane >> 5;
  if (tid < HDIM) {
    ssum[tid] = 0.f; ssq[tid] = 0.f;
    sTop[tid] = top_idx[m0 + tid];
  }
  {
    const int g = tid & 15, r0 = tid >> 4;
    const float4 sc0 = *(const float4*)(scaleA + e * HDIM + g * 8);
    const float4 sc1 = *(const float4*)(scaleA + e * HDIM + g * 8 + 4);
    const float4 sh0 = *(const float4*)(shiftA + e * HDIM + g * 8);
    const float4 sh1 = *(const float4*)(shiftA + e * HDIM + g * 8 + 4);
#pragma unroll
    for (int c = 0; c < 8; ++c) {
      const int m = c * 16 + r0;
      const short8 hq = *(const short8*)(
          h1 + ((size_t)e * NNODES + m0 + m) * HDIM + g * 8);
      short8 pk;
      pk[0] = (short)f2bf(fmaxf(0.f, fmaf(bf2f((ushort_t)hq[0]), sc0.x, sh0.x)));
      pk[1] = (short)f2bf(fmaxf(0.f, fmaf(bf2f((ushort_t)hq[1]), sc0.y, sh0.y)));
      pk[2] = (short)f2bf(fmaxf(0.f, fmaf(bf2f((ushort_t)hq[2]), sc0.z, sh0.z)));
      pk[3] = (short)f2bf(fmaxf(0.f, fmaf(bf2f((ushort_t)hq[3]), sc0.w, sh0.w)));
      pk[4] = (short)f2bf(fmaxf(0.f, fmaf(bf2f((ushort_t)hq[4]), sc1.x, sh1.x)));
      pk[5] = (short)f2bf(fmaxf(0.f, fmaf(bf2f((ushort_t)hq[5]), sc1.y, sh1.y)));
      pk[6] = (short)f2bf(fmaxf(0.f, fmaf(bf2f((ushort_t)hq[6]), sc1.z, sh1.z)));
      pk[7] = (short)f2bf(fmaxf(0.f, fmaf(bf2f((ushort_t)hq[7]), sc1.w, sh1.w)));
      *(short8*)(sA + (size_t)(g * 129 + m) * 8) = pk;
    }
  }
  __syncthreads();

  floatx16 acc[2][2];
#pragma unroll
  for (int i = 0; i < 2; ++i)
#pragma unroll
    for (int j = 0; j < 2; ++j)
#pragma unroll
      for (int r = 0; r < 16; ++r) acc[i][j][r] = 0.f;

  const ushort_t* bte = Bt2 + ((size_t)e * KS2 * 256 + half * 128 + wn * 64 + l31) * 8;
  short8 nb0 = *(const short8*)(bte);
  short8 nb1 = *(const short8*)(bte + 32 * 8);
#pragma unroll
  for (int ks = 0; ks < KS2; ++ks) {
    const short8 b0 = nb0, b1 = nb1;
    if (ks < KS2 - 1) {
      nb0 = *(const short8*)(bte + (size_t)((ks + 1) * 256) * 8);
      nb1 = *(const short8*)(bte + (size_t)((ks + 1) * 256 + 32) * 8);
    }
    const short8 a0 = *(const short8*)(sA + (size_t)((2 * ks + half) * 129 + wm * 64 + l31) * 8);
    const short8 a1 = *(const short8*)(sA + (size_t)((2 * ks + half) * 129 + wm * 64 + 32 + l31) * 8);
    acc[0][0] = __builtin_amdgcn_mfma_f32_32x32x16_bf16(a0, b0, acc[0][0], 0, 0, 0);
    acc[0][1] = __builtin_amdgcn_mfma_f32_32x32x16_bf16(a0, b1, acc[0][1], 0, 0, 0);
    acc[1][0] = __builtin_amdgcn_mfma_f32_32x32x16_bf16(a1, b0, acc[1][0], 0, 0, 0);
    acc[1][1] = __builtin_amdgcn_mfma_f32_32x32x16_bf16(a1, b1, acc[1][1], 0, 0, 0);
  }

#pragma unroll
  for (int ms = 0; ms < 2; ++ms)
#pragma unroll
    for (int ns = 0; ns < 2; ++ns) {
      const int col = wn * 64 + ns * 32 + l31;
      float s = 0.f, q = 0.f;
#pragma unroll
      for (int r = 0; r < 16; ++r) {
        const int row = wm * 64 + ms * 32 + (r & 3) + 8 * (r >> 2) + 4 * half;
        const float x = acc[ms][ns][r];
        if (sTop[row] == e) h2_sel[(size_t)(m0 + row) * HDIM + col] = x;
        s += x; q = fmaf(x, x, q);
      }
      atomicAdd(&ssum[col], s);
      atomicAdd(&ssq[col], q);
    }
  __syncthreads();
  if (tid < HDIM) atomicAdd(&sum2[e * HDIM + tid], ssum[tid]);
  else            atomicAdd(&sq2[e * HDIM + tid - HDIM], ssq[tid - HDIM]);
}

// --------------------------------------------------------- combine + loss
__global__ __launch_bounds__(256) void combine_kernel(
    const float* __restrict__ h2_sel, const int* __restrict__ top_idx,
    const float* __restrict__ top_val, const float* __restrict__ scale2,
    const float* __restrict__ shift2, float* __restrict__ out)
{
  const int i4 = (blockIdx.x * 256 + threadIdx.x) * 4;
  const int n = i4 >> 7, h = i4 & 127;
  const int e = top_idx[n];
  const float tv = top_val[n];
  const float4 x = *(const float4*)(h2_sel + i4);
  const float* sc = scale2 + e * HDIM + h;
  const float* sh = shift2 + e * HDIM + h;
  float4 o;
  o.x = tv * fmaxf(0.f, fmaf(x.x, sc[0], sh[0]));
  o.y = tv * fmaxf(0.f, fmaf(x.y, sc[1], sh[1]));
  o.z = tv * fmaxf(0.f, fmaf(x.z, sc[2], sh[2]));
  o.w = tv * fmaxf(0.f, fmaf(x.w, sc[3], sh[3]));
  *(float4*)(out + i4) = o;
}

__global__ void loss_kernel(const float* __restrict__ imp,
                            const float* __restrict__ cnt,
                            const float* __restrict__ tv,
                            float* __restrict__ out_losses)
{
  if (threadIdx.x == 0) {
    const float invN = 1.f / (float)NNODES;
    float bal = 0.f;
#pragma unroll
    for (int e = 0; e < NEXP; ++e) bal += (imp[e] * invN) * (cnt[e] * invN);
    out_losses[0] = 0.01f * (float)NEXP * bal;
    out_losses[1] = -0.01f * tv[0] * invN;
  }
}

// ----------------------------------------------------------------- launch
struct WS {
  ushort_t *v_bf, *agg_bf, *h1, *Bt1x, *Bt2;
  float *h2_sel;
  int2 *cv, *tmp;
  int *row_start, *cursors, *cursA, *top_idx, *incl, *bsum, *boff;
  float *top_val;
  char *zero_base; size_t zero_bytes;
  int *counts;
  float *sum1, *sq1, *sum2, *sq2, *imp, *cnt, *tv;
  float *scaleA, *shiftA, *scale2, *shift2;
  size_t total;
};

static WS carve_ws(char* base, int ne)
{
  WS w; size_t off = 0;
  auto take = [&](size_t b) -> char* {
    char* r = base + off; off += (b + 255) & ~(size_t)255; return r;
  };
  w.v_bf   = (ushort_t*)take((size_t)NNODES * CPAD * 2);
  w.agg_bf = (ushort_t*)take((size_t)NNODES * CPAD * 2);
  w.h2_sel = (float*)w.v_bf;
  w.h1     = (ushort_t*)take((size_t)NEXP * NNODES * HDIM * 2);
  w.cv     = (int2*)take((size_t)ne * 8);
  w.tmp    = (int2*)take((size_t)ne * 8);
  w.Bt1x   = (ushort_t*)take((size_t)NEXP * KC1 * 2048 * 2);
  w.Bt2    = (ushort_t*)take((size_t)NEXP * KS2 * 2048 * 2);
  w.row_start= (int*)take(NNODES * 4);
  w.cursors  = (int*)take(NNODES * 4);
  w.cursA    = (int*)take(NB * 4);
  w.top_idx  = (int*)take(NNODES * 4);
  w.top_val  = (float*)take(NNODES * 4);
  w.incl     = (int*)take(NNODES * 4);
  w.bsum     = (int*)take(64 * 4);
  w.boff     = (int*)take(64 * 4);
  w.zero_base = base + off;
  w.counts = (int*)take(NNODES * 4);
  w.sum1 = (float*)take(NEXP * HDIM * 4);
  w.sq1  = (float*)take(NEXP * HDIM * 4);
  w.sum2 = (float*)take(NEXP * HDIM * 4);
  w.sq2  = (float*)take(NEXP * HDIM * 4);
  w.imp  = (float*)take(NEXP * 4);
  w.cnt  = (float*)take(NEXP * 4);
  w.tv   = (float*)take(4);
  w.zero_bytes = (size_t)((base + off) - w.zero_base);
  w.scaleA = (float*)take(NEXP * HDIM * 4);
  w.shiftA = (float*)take(NEXP * HDIM * 4);
  w.scale2 = (float*)take(NEXP * HDIM * 4);
  w.shift2 = (float*)take(NEXP * HDIM * 4);
  w.total = off;
  return w;
}

extern "C" void kernel_launch(void* const* d_in, const int* in_sizes, int n_in,
                              void* d_out, int out_size, void* d_ws, size_t ws_size,
                              hipStream_t stream)
{
  const float* v      = (const float*)d_in[0];
  const int*   a_rows = (const int*)d_in[1];
  const int*   a_cols = (const int*)d_in[2];
  const float* a_vals = (const float*)d_in[3];
  const float* gate_W = (const float*)d_in[4];
  const float* gate_b = (const float*)d_in[5];
  const float* eps    = (const float*)d_in[6];
  const float* W1     = (const float*)d_in[7];
  const float* g1     = (const float*)d_in[9];
  const float* beta1  = (const float*)d_in[10];
  const float* W2     = (const float*)d_in[11];
  const float* g2     = (const float*)d_in[13];
  const float* beta2  = (const float*)d_in[14];
  const int NE = in_sizes[1];
  float* out = (float*)d_out;
  (void)n_in; (void)out_size; (void)ws_size;

  WS w = carve_ws((char*)d_ws, NE);

  hipMemsetAsync(w.zero_base, 0, w.zero_bytes, stream);

  gating_kernel<<<NNODES / 64, 256, 0, stream>>>(
      v, gate_W, gate_b, w.top_idx, w.top_val, w.v_bf, w.imp, w.cnt, w.tv);
  btconv1x_kernel<<<dim3(KC1, NEXP), 256, 0, stream>>>(W1, eps, w.Bt1x);
  btconv_kernel<<<dim3(KS2, NEXP), 256, 0, stream>>>(W2, w.Bt2, HDIM, KS2);
  hist_kernel<<<(NE + 255) / 256, 256, 0, stream>>>(a_rows, w.counts, NE);
  scan_block_kernel<<<NNODES / 1024, 1024, 0, stream>>>(w.counts, w.incl, w.bsum);
  scan_tops_kernel<<<1, 64, 0, stream>>>(w.bsum, w.boff, NNODES / 1024);
  scan_apply_kernel<<<NNODES / 256, 256, 0, stream>>>(
      w.incl, w.boff, w.counts, w.row_start, w.cursors, w.cursA);
  bucketA_kernel<<<(NE + EPB - 1) / EPB, 256, 0, stream>>>(
      a_rows, a_cols, a_vals, w.cursA, w.tmp, NE);
  bucketB_kernel<<<NB, 256, 0, stream>>>(
      w.tmp, w.row_start, w.cursors, w.cv, NE);
  aggregate_kernel<<<NNODES / 4, 256, 0, stream>>>(
      w.v_bf, w.cv, w.row_start, w.counts, w.agg_bf);

  gemm1_mfma<<<NNODES / 64, 256, 0, stream>>>(
      w.agg_bf, w.v_bf, w.Bt1x, w.h1, w.sum1, w.sq1);
  finalize_kernel<<<NEXP, 128, 0, stream>>>(
      w.sum1, w.sq1, g1, beta1, w.scaleA, w.shiftA);
  gemm2_mfma<<<dim3(NNODES / 128, NEXP), 256, 0, stream>>>(
      w.h1, w.Bt2, w.scaleA, w.shiftA, w.top_idx, w.h2_sel, w.sum2, w.sq2);
  finalize_kernel<<<NEXP, 128, 0, stream>>>(
      w.sum2, w.sq2, g2, beta2, w.scale2, w.shift2);

  combine_kernel<<<(NNODES * HDIM) / 1024, 256, 0, stream>>>(
      w.h2_sel, w.top_idx, w.top_val, w.scale2, w.shift2, out);
  loss_kernel<<<1, 64, 0, stream>>>(w.imp, w.cnt, w.tv, out + (size_t)NNODES * HDIM);
}